// Round 1
// baseline (612.983 us; speedup 1.0000x reference)
//
#include <hip/hip_runtime.h>

#define H_  16
#define L_  1024
#define D_  1024
#define DH  64

typedef short bf16x8 __attribute__((ext_vector_type(8)));
typedef float f32x4  __attribute__((ext_vector_type(4)));

__device__ __forceinline__ ushort f2bf(float f) {
  union { float f; unsigned int u; } x; x.f = f;
  unsigned int u = x.u;
  u = (u + 0x7fffu + ((u >> 16) & 1u)) >> 16;   // RNE, matches numpy/HIP
  return (ushort)u;
}
__device__ __forceinline__ float bf2f(ushort s) {
  union { unsigned int u; float f; } x; x.u = ((unsigned int)s) << 16;
  return x.f;
}

__global__ __launch_bounds__(256) void cvt_bf16_kernel(const float* __restrict__ in,
                                                       ushort* __restrict__ out, int n) {
  int i = blockIdx.x * 256 + threadIdx.x;
  if (i < n) out[i] = f2bf(in[i]);
}

// C[4096x1024] = A[4096x1024] @ B[1024x1024]; A fp32 or bf16, B fp32 (converted on stage), C bf16 or fp32.
template<bool AF32, bool OF32>
__global__ __launch_bounds__(256) void gemm_kernel(const void* __restrict__ Ap,
                                                   const float* __restrict__ B,
                                                   void* __restrict__ Cp) {
  __shared__ ushort lsA[128][40];   // [row][k], pad 40
  __shared__ ushort lsB[128][40];   // [n][k] transposed, pad 40
  const int tid  = threadIdx.x;
  const int w    = tid >> 6, lane = tid & 63, qd = lane >> 4, ln = lane & 15;
  const int rw   = w >> 1, cw = w & 1;
  const int m0   = blockIdx.y * 128, n0 = blockIdx.x * 128;

  f32x4 acc[16];
#pragma unroll
  for (int i = 0; i < 16; ++i) acc[i] = (f32x4){0.f, 0.f, 0.f, 0.f};

  for (int kb = 0; kb < 32; ++kb) {
    const int k0 = kb * 32;
    // ---- stage A tile [128 x 32] -> bf16 LDS
    {
      int row = tid >> 1, half = tid & 1;
      if (AF32) {
        const float* A = (const float*)Ap;
#pragma unroll
        for (int c = 0; c < 4; ++c) {
          float4 f = *(const float4*)(A + (size_t)(m0 + row) * 1024 + k0 + half * 16 + c * 4);
          ushort4 u;
          u.x = f2bf(f.x); u.y = f2bf(f.y); u.z = f2bf(f.z); u.w = f2bf(f.w);
          *(ushort4*)(&lsA[row][half * 16 + c * 4]) = u;
        }
      } else {
        const ushort* A = (const ushort*)Ap;
#pragma unroll
        for (int c = 0; c < 2; ++c) {
          uint4 u = *(const uint4*)(A + (size_t)(m0 + row) * 1024 + k0 + half * 16 + c * 8);
          *(uint4*)(&lsA[row][half * 16 + c * 8]) = u;
        }
      }
    }
    // ---- stage B tile [32 x 128] fp32 -> transposed bf16 LDS [n][k]
    {
      int kk = tid >> 3, nb = (tid & 7) * 16;
      float vals[16];
#pragma unroll
      for (int c = 0; c < 4; ++c) {
        float4 f = *(const float4*)(B + (size_t)(k0 + kk) * 1024 + n0 + nb + c * 4);
        vals[c * 4 + 0] = f.x; vals[c * 4 + 1] = f.y;
        vals[c * 4 + 2] = f.z; vals[c * 4 + 3] = f.w;
      }
#pragma unroll
      for (int e = 0; e < 16; ++e) lsB[nb + e][kk] = f2bf(vals[e]);
    }
    __syncthreads();
    // ---- compute: wave tile 64x64 = 4x4 frags of 16x16
    bf16x8 afr[4], bfr[4];
#pragma unroll
    for (int am = 0; am < 4; ++am)
      afr[am] = *(const bf16x8*)(&lsA[rw * 64 + am * 16 + ln][qd * 8]);
#pragma unroll
    for (int bn = 0; bn < 4; ++bn)
      bfr[bn] = *(const bf16x8*)(&lsB[cw * 64 + bn * 16 + ln][qd * 8]);
#pragma unroll
    for (int am = 0; am < 4; ++am)
#pragma unroll
      for (int bn = 0; bn < 4; ++bn)
        acc[am * 4 + bn] = __builtin_amdgcn_mfma_f32_16x16x32_bf16(afr[am], bfr[bn], acc[am * 4 + bn], 0, 0, 0);
    __syncthreads();
  }
  // ---- epilogue: C row = qd*4+r, col = ln within each 16x16 frag
#pragma unroll
  for (int am = 0; am < 4; ++am)
#pragma unroll
    for (int bn = 0; bn < 4; ++bn)
#pragma unroll
      for (int r = 0; r < 4; ++r) {
        int row = m0 + rw * 64 + am * 16 + qd * 4 + r;
        int col = n0 + cw * 64 + bn * 16 + ln;
        if (OF32) ((float*)Cp)[(size_t)row * 1024 + col] = acc[am * 4 + bn][r];
        else      ((ushort*)Cp)[(size_t)row * 1024 + col] = f2bf(acc[am * 4 + bn][r]);
      }
}

// Fused relative attention. One workgroup = one (b,h) and a 16-row Q tile.
// q/kT/v are CONTIGUOUS slabs (reference uses plain reshape): q[1024][64], kT[64][1024], v[1024][64].
__global__ __launch_bounds__(256) void attn_kernel(
    const ushort* __restrict__ QW, const ushort* __restrict__ KW,
    const ushort* __restrict__ VW, const ushort* __restrict__ Erb,
    ushort* __restrict__ Om) {
  __shared__ ushort lq[32][72];     // q rows i0..i0+31 (clamped), pad 72
  __shared__ ushort qp[17][1028];   // QEr rows i0..i0+16; later aliased as P[16][1024] (pad 1028)
  __shared__ float  stats[2][4][16];

  const int tid = threadIdx.x;
  const int w   = tid >> 6;
  const int lane = tid & 63;
  const int qd  = lane >> 4;
  const int ln  = lane & 15;
  const int bh  = blockIdx.y;
  const int i0  = blockIdx.x << 4;
  const ushort* q  = QW + ((size_t)bh << 16);
  const ushort* kT = KW + ((size_t)bh << 16);
  const ushort* v  = VW + ((size_t)bh << 16);

  { // stage q rows i0..i0+31
    int r = tid >> 3;
    int c = (tid & 7) << 3;
    int row = i0 + r; if (row > L_ - 1) row = L_ - 1;
    *(uint4*)(&lq[r][c]) = *(const uint4*)(q + (size_t)row * DH + c);
  }
  __syncthreads();

  // ---- phase 0: QEr rows 0..16 -> qp (row-block 1 only contributes local row 0 = global i0+16)
  for (int rb = 0; rb < 2; ++rb) {
    bf16x8 a0 = *(const bf16x8*)(&lq[rb * 16 + ln][qd * 8]);
    bf16x8 a1 = *(const bf16x8*)(&lq[rb * 16 + ln][32 + qd * 8]);
    for (int f = 0; f < 16; ++f) {
      int m = (f >> 2) * 256 + (((f & 3) * 4 + w) << 4) + ln;   // Er row index (= QEr col)
      bf16x8 b0 = *(const bf16x8*)(Erb + (size_t)m * DH + qd * 8);
      bf16x8 b1 = *(const bf16x8*)(Erb + (size_t)m * DH + 32 + qd * 8);
      f32x4 acc = {0.f, 0.f, 0.f, 0.f};
      acc = __builtin_amdgcn_mfma_f32_16x16x32_bf16(a0, b0, acc, 0, 0, 0);
      acc = __builtin_amdgcn_mfma_f32_16x16x32_bf16(a1, b1, acc, 0, 0, 0);
      if (rb == 0) {
#pragma unroll
        for (int r = 0; r < 4; ++r) qp[qd * 4 + r][m] = f2bf(acc[r]);
      } else if (qd == 0) {
        qp[16][m] = f2bf(acc[0]);
      }
    }
  }
  __syncthreads();

  // ---- phase 1: S = q @ kT (kT B-frags straight from global; L2-hot)
  bf16x8 as0 = *(const bf16x8*)(&lq[ln][qd * 8]);
  bf16x8 as1 = *(const bf16x8*)(&lq[ln][32 + qd * 8]);
  f32x4 sfr[16];
#pragma unroll
  for (int f = 0; f < 16; ++f) {
    int j = (f >> 2) * 256 + (((f & 3) * 4 + w) << 4) + ln;
    bf16x8 b0, b1;
#pragma unroll
    for (int jj = 0; jj < 8; ++jj) {
      b0[jj] = (short)kT[(size_t)(qd * 8 + jj) * L_ + j];
      b1[jj] = (short)kT[(size_t)(32 + qd * 8 + jj) * L_ + j];
    }
    f32x4 acc = {0.f, 0.f, 0.f, 0.f};
    acc = __builtin_amdgcn_mfma_f32_16x16x32_bf16(as0, b0, acc, 0, 0, 0);
    acc = __builtin_amdgcn_mfma_f32_16x16x32_bf16(as1, b1, acc, 0, 0, 0);
    sfr[f] = acc;
  }

  // ---- skew-add Srel + scale 1/sqrt(64)
#pragma unroll
  for (int f = 0; f < 16; ++f) {
    int j = (f >> 2) * 256 + (((f & 3) * 4 + w) << 4) + ln;
#pragma unroll
    for (int r = 0; r < 4; ++r) {
      int rloc = qd * 4 + r;
      int i = i0 + rloc;
      float srel;
      if (j <= i)          srel = bf2f(qp[rloc][1023 - i + j]);
      else if (j == i + 1) srel = 0.f;
      else                 srel = bf2f(qp[rloc + 1][j - i - 2]);
      sfr[f][r] = (sfr[f][r] + srel) * 0.125f;
    }
  }

  // ---- row max (lanes of a quad hold rows qd*4+r)
  {
    float vm[4];
#pragma unroll
    for (int r = 0; r < 4; ++r) {
      float m = sfr[0][r];
#pragma unroll
      for (int f = 1; f < 16; ++f) m = fmaxf(m, sfr[f][r]);
#pragma unroll
      for (int off = 1; off < 16; off <<= 1) m = fmaxf(m, __shfl_xor(m, off, 64));
      vm[r] = m;
    }
    if (ln == 0) {
#pragma unroll
      for (int r = 0; r < 4; ++r) stats[0][w][qd * 4 + r] = vm[r];
    }
  }
  __syncthreads();   // stats ready; all qp(QEr) reads done -> safe to overwrite as P
  float gm[4];
#pragma unroll
  for (int r = 0; r < 4; ++r) {
    float m = stats[0][0][qd * 4 + r];
    m = fmaxf(m, stats[0][1][qd * 4 + r]);
    m = fmaxf(m, stats[0][2][qd * 4 + r]);
    m = fmaxf(m, stats[0][3][qd * 4 + r]);
    gm[r] = m;
  }

  // ---- exp, row sum, write P (unnormalized) into qp alias
  float vs[4] = {0.f, 0.f, 0.f, 0.f};
#pragma unroll
  for (int f = 0; f < 16; ++f) {
    int j = (f >> 2) * 256 + (((f & 3) * 4 + w) << 4) + ln;
#pragma unroll
    for (int r = 0; r < 4; ++r) {
      float e = __expf(sfr[f][r] - gm[r]);
      vs[r] += e;
      qp[qd * 4 + r][j] = f2bf(e);
    }
  }
#pragma unroll
  for (int r = 0; r < 4; ++r) {
    float s = vs[r];
#pragma unroll
    for (int off = 1; off < 16; off <<= 1) s += __shfl_xor(s, off, 64);
    if (ln == 0) stats[1][w][qd * 4 + r] = s;
  }
  __syncthreads();   // P + sums ready
  float rrl[4];
#pragma unroll
  for (int r = 0; r < 4; ++r) {
    float s = stats[1][0][qd * 4 + r] + stats[1][1][qd * 4 + r] +
              stats[1][2][qd * 4 + r] + stats[1][3][qd * 4 + r];
    rrl[r] = 1.0f / s;
  }

  // ---- phase 3: O = P @ v, wave w owns d-chunk [w*16, w*16+16)
  f32x4 oacc = {0.f, 0.f, 0.f, 0.f};
#pragma unroll 4
  for (int ks = 0; ks < 32; ++ks) {
    bf16x8 ap = *(const bf16x8*)(&qp[ln][ks * 32 + qd * 8]);
    bf16x8 bv;
#pragma unroll
    for (int jj = 0; jj < 8; ++jj)
      bv[jj] = (short)v[(size_t)(ks * 32 + qd * 8 + jj) * DH + w * 16 + ln];
    oacc = __builtin_amdgcn_mfma_f32_16x16x32_bf16(ap, bv, oacc, 0, 0, 0);
  }

  // ---- store merged-head layout O[b][row][h*64 + dd]
  const int b = bh >> 4, h = bh & 15;
  ushort* ob = Om + ((size_t)b * L_ * D_) + (size_t)h * DH + (size_t)(w * 16 + ln);
#pragma unroll
  for (int r = 0; r < 4; ++r) {
    int row = i0 + qd * 4 + r;
    ob[(size_t)row * D_] = f2bf(oacc[r] * rrl[r]);
  }
}

extern "C" void kernel_launch(void* const* d_in, const int* in_sizes, int n_in,
                              void* d_out, int out_size, void* d_ws, size_t ws_size,
                              hipStream_t stream) {
  const float* query = (const float*)d_in[0];
  const float* key   = (const float*)d_in[1];
  const float* value = (const float*)d_in[2];
  const float* WQ    = (const float*)d_in[3];
  const float* WK    = (const float*)d_in[4];
  const float* WV    = (const float*)d_in[5];
  const float* Er    = (const float*)d_in[6];
  const float* WM    = (const float*)d_in[7];
  float* out = (float*)d_out;

  // workspace layout (bf16 buffers): QW,KW,VW,O (4M ushorts each) + Er (64K) = ~32.1 MB
  ushort* QW  = (ushort*)d_ws;
  ushort* KW  = QW + (size_t)4096 * 1024;
  ushort* VW  = KW + (size_t)4096 * 1024;
  ushort* O   = VW + (size_t)4096 * 1024;
  ushort* Erb = O  + (size_t)4096 * 1024;

  cvt_bf16_kernel<<<256, 256, 0, stream>>>(Er, Erb, L_ * DH);

  dim3 gg(8, 32);   // N/128, M/128
  gemm_kernel<true, false><<<gg, 256, 0, stream>>>(query, WQ, QW);
  gemm_kernel<true, false><<<gg, 256, 0, stream>>>(key,   WK, KW);
  gemm_kernel<true, false><<<gg, 256, 0, stream>>>(value, WV, VW);

  attn_kernel<<<dim3(64, 64), 256, 0, stream>>>(QW, KW, VW, Erb, O);

  gemm_kernel<false, true><<<gg, 256, 0, stream>>>(O, WM, out);
}

// Round 2
// 565.162 us; speedup vs baseline: 1.0846x; 1.0846x over previous
//
#include <hip/hip_runtime.h>

#define H_  16
#define L_  1024
#define D_  1024
#define DH  64

typedef short bf16x8 __attribute__((ext_vector_type(8)));
typedef float f32x4  __attribute__((ext_vector_type(4)));

__device__ __forceinline__ ushort f2bf(float f) {
  union { float f; unsigned int u; } x; x.f = f;
  unsigned int u = x.u;
  u = (u + 0x7fffu + ((u >> 16) & 1u)) >> 16;   // RNE
  return (ushort)u;
}
__device__ __forceinline__ float bf2f(ushort s) {
  union { unsigned int u; float f; } x; x.u = ((unsigned int)s) << 16;
  return x.f;
}

__global__ __launch_bounds__(256) void cvt_bf16_kernel(const float* __restrict__ in,
                                                       ushort* __restrict__ out, int n) {
  int i = blockIdx.x * 256 + threadIdx.x;
  if (i < n) out[i] = f2bf(in[i]);
}

// W fp32 [1024][1024] row-major -> WT bf16 [n][k] (transposed)
__global__ __launch_bounds__(256) void wT_kernel(const float* __restrict__ W,
                                                 ushort* __restrict__ WT) {
  __shared__ ushort tt[64][72];
  const int t = threadIdx.x;
  const int k0 = blockIdx.y * 64, n0 = blockIdx.x * 64;
#pragma unroll
  for (int c = 0; c < 4; ++c) {
    int k = c * 16 + (t >> 4);
    float4 f = *(const float4*)(W + (size_t)(k0 + k) * 1024 + n0 + (t & 15) * 4);
    tt[(t & 15) * 4 + 0][k] = f2bf(f.x);
    tt[(t & 15) * 4 + 1][k] = f2bf(f.y);
    tt[(t & 15) * 4 + 2][k] = f2bf(f.z);
    tt[(t & 15) * 4 + 3][k] = f2bf(f.w);
  }
  __syncthreads();
#pragma unroll
  for (int p = 0; p < 2; ++p) {
    int n = p * 32 + (t >> 3);
    *(uint4*)(WT + (size_t)(n0 + n) * 1024 + k0 + (t & 7) * 8) = *(const uint4*)(&tt[n][(t & 7) * 8]);
  }
}

#define OUT_BF16 0
#define OUT_KT   1
#define OUT_VT   2
#define OUT_F32  3

// C[4096x1024] = A[4096x1024] @ B[1024x1024]; A fp32 or bf16; B passed as bf16 BT[n][k].
template<bool AF32, int OMODE>
__global__ __launch_bounds__(256) void gemm_kernel(const void* __restrict__ Ap,
                                                   const ushort* __restrict__ BT,
                                                   void* __restrict__ Cp) {
  __shared__ ushort lsA[128][40];   // [row][k], pad 40
  __shared__ ushort lsB[128][40];   // [n][k], pad 40
  const int tid  = threadIdx.x;
  const int w    = tid >> 6, lane = tid & 63, qd = lane >> 4, ln = lane & 15;
  const int rw   = w >> 1, cw = w & 1;
  const int m0   = blockIdx.y * 128, n0 = blockIdx.x * 128;

  f32x4 acc[16];
#pragma unroll
  for (int i = 0; i < 16; ++i) acc[i] = (f32x4){0.f, 0.f, 0.f, 0.f};

  for (int kb = 0; kb < 32; ++kb) {
    const int k0 = kb * 32;
    // ---- stage A tile [128 x 32] -> bf16 LDS
    {
      int row = tid >> 1, half = tid & 1;
      if (AF32) {
        const float* A = (const float*)Ap;
#pragma unroll
        for (int c = 0; c < 4; ++c) {
          float4 f = *(const float4*)(A + (size_t)(m0 + row) * 1024 + k0 + half * 16 + c * 4);
          ushort4 u;
          u.x = f2bf(f.x); u.y = f2bf(f.y); u.z = f2bf(f.z); u.w = f2bf(f.w);
          *(ushort4*)(&lsA[row][half * 16 + c * 4]) = u;
        }
      } else {
        const ushort* A = (const ushort*)Ap;
#pragma unroll
        for (int c = 0; c < 2; ++c) {
          uint4 u = *(const uint4*)(A + (size_t)(m0 + row) * 1024 + k0 + half * 16 + c * 8);
          *(uint4*)(&lsA[row][half * 16 + c * 8]) = u;
        }
      }
    }
    // ---- stage B tile: BT[n][k] bf16, vectorized copy
    {
      int row = tid >> 1, half = tid & 1;
#pragma unroll
      for (int c = 0; c < 2; ++c)
        *(uint4*)(&lsB[row][half * 16 + c * 8]) =
            *(const uint4*)(BT + (size_t)(n0 + row) * 1024 + k0 + half * 16 + c * 8);
    }
    __syncthreads();
    // ---- compute: wave tile 64x64 = 4x4 frags of 16x16
    bf16x8 afr[4], bfr[4];
#pragma unroll
    for (int am = 0; am < 4; ++am)
      afr[am] = *(const bf16x8*)(&lsA[rw * 64 + am * 16 + ln][qd * 8]);
#pragma unroll
    for (int bn = 0; bn < 4; ++bn)
      bfr[bn] = *(const bf16x8*)(&lsB[cw * 64 + bn * 16 + ln][qd * 8]);
#pragma unroll
    for (int am = 0; am < 4; ++am)
#pragma unroll
      for (int bn = 0; bn < 4; ++bn)
        acc[am * 4 + bn] = __builtin_amdgcn_mfma_f32_16x16x32_bf16(afr[am], bfr[bn], acc[am * 4 + bn], 0, 0, 0);
    __syncthreads();
  }
  // ---- epilogue
#pragma unroll
  for (int am = 0; am < 4; ++am)
#pragma unroll
    for (int bn = 0; bn < 4; ++bn) {
      const int rbase = m0 + rw * 64 + am * 16 + qd * 4;       // + r
      const int colg  = n0 + cw * 64 + bn * 16 + ln;
      if (OMODE == OUT_F32) {
#pragma unroll
        for (int r = 0; r < 4; ++r)
          ((float*)Cp)[(size_t)(rbase + r) * 1024 + colg] = acc[am * 4 + bn][r];
      } else if (OMODE == OUT_BF16) {
#pragma unroll
        for (int r = 0; r < 4; ++r)
          ((ushort*)Cp)[(size_t)(rbase + r) * 1024 + colg] = f2bf(acc[am * 4 + bn][r]);
      } else if (OMODE == OUT_KT) {
        // kT slab [64][1024] transposed -> KT[j][ki] at bh*65536 + j*64 + ki
        const int bh = rbase >> 6;
        const int ki = rbase & 63;                              // + r (contiguous)
        ushort4 u;
        u.x = f2bf(acc[am * 4 + bn][0]); u.y = f2bf(acc[am * 4 + bn][1]);
        u.z = f2bf(acc[am * 4 + bn][2]); u.w = f2bf(acc[am * 4 + bn][3]);
        *(ushort4*)((ushort*)Cp + (size_t)bh * 65536 + (size_t)colg * 64 + ki) = u;
      } else { // OUT_VT: v slab [1024][64] transposed -> VT[ki][lv] at bh*65536 + ki*1024 + lv
        const int bh = rbase >> 6;
#pragma unroll
        for (int r = 0; r < 4; ++r) {
          int lv = ((rbase + r) & 63) * 16 + (colg >> 6);
          int ki = colg & 63;
          ((ushort*)Cp)[(size_t)bh * 65536 + (size_t)ki * 1024 + lv] = f2bf(acc[am * 4 + bn][r]);
        }
      }
    }
}

// Fused relative attention. One workgroup = one (b,h) slab and a 16-row Q tile.
// q slab [1024][64]; kT passed transposed KT[j=1024][k=64]; v passed transposed VT[dd=64][l=1024].
__global__ __launch_bounds__(256) void attn_kernel(
    const ushort* __restrict__ QW, const ushort* __restrict__ KTg,
    const ushort* __restrict__ VTg, const ushort* __restrict__ Erb,
    ushort* __restrict__ Om) {
  __shared__ ushort lq[32][72];     // q rows i0..i0+31 (clamped), pad 72
  __shared__ ushort qp[17][1032];   // QEr rows i0..i0+16; later aliased as P[16][1024]
  __shared__ float  stats[2][4][16];

  const int tid = threadIdx.x;
  const int w   = tid >> 6;
  const int lane = tid & 63;
  const int qd  = lane >> 4;
  const int ln  = lane & 15;
  const int bh  = blockIdx.y;
  const int i0  = blockIdx.x << 4;
  const ushort* q  = QW  + ((size_t)bh << 16);
  const ushort* kT = KTg + ((size_t)bh << 16);
  const ushort* vT = VTg + ((size_t)bh << 16);

  { // stage q rows i0..i0+31
    int r = tid >> 3;
    int c = (tid & 7) << 3;
    int row = i0 + r; if (row > L_ - 1) row = L_ - 1;
    *(uint4*)(&lq[r][c]) = *(const uint4*)(q + (size_t)row * DH + c);
  }
  __syncthreads();

  // ---- phase 0: QEr rows 0..16 -> qp
  for (int rb = 0; rb < 2; ++rb) {
    bf16x8 a0 = *(const bf16x8*)(&lq[rb * 16 + ln][qd * 8]);
    bf16x8 a1 = *(const bf16x8*)(&lq[rb * 16 + ln][32 + qd * 8]);
    for (int f = 0; f < 16; ++f) {
      int mb = (f >> 2) * 256 + (((f & 3) * 4 + w) << 4);
      if (rb == 1 && mb > 1006 - i0) continue;   // row i0+16 prefix only needs cols <= 1006-i0
      int m = mb + ln;
      bf16x8 b0 = *(const bf16x8*)(Erb + (size_t)m * DH + qd * 8);
      bf16x8 b1 = *(const bf16x8*)(Erb + (size_t)m * DH + 32 + qd * 8);
      f32x4 acc = {0.f, 0.f, 0.f, 0.f};
      acc = __builtin_amdgcn_mfma_f32_16x16x32_bf16(a0, b0, acc, 0, 0, 0);
      acc = __builtin_amdgcn_mfma_f32_16x16x32_bf16(a1, b1, acc, 0, 0, 0);
      if (rb == 0) {
#pragma unroll
        for (int r = 0; r < 4; ++r) qp[qd * 4 + r][m] = f2bf(acc[r]);
      } else if (qd == 0) {
        qp[16][m] = f2bf(acc[0]);
      }
    }
  }
  __syncthreads();

  // ---- phase 1: S = q @ kT (KT[j][k] -> vectorized B-frag loads)
  bf16x8 as0 = *(const bf16x8*)(&lq[ln][qd * 8]);
  bf16x8 as1 = *(const bf16x8*)(&lq[ln][32 + qd * 8]);
  f32x4 sfr[16];
#pragma unroll
  for (int f = 0; f < 16; ++f) {
    int j = (f >> 2) * 256 + (((f & 3) * 4 + w) << 4) + ln;
    bf16x8 b0 = *(const bf16x8*)(kT + (size_t)j * 64 + qd * 8);
    bf16x8 b1 = *(const bf16x8*)(kT + (size_t)j * 64 + 32 + qd * 8);
    f32x4 acc = {0.f, 0.f, 0.f, 0.f};
    acc = __builtin_amdgcn_mfma_f32_16x16x32_bf16(as0, b0, acc, 0, 0, 0);
    acc = __builtin_amdgcn_mfma_f32_16x16x32_bf16(as1, b1, acc, 0, 0, 0);
    sfr[f] = acc;
  }

  // ---- skew-add Srel + scale 1/sqrt(64)
#pragma unroll
  for (int f = 0; f < 16; ++f) {
    int j = (f >> 2) * 256 + (((f & 3) * 4 + w) << 4) + ln;
#pragma unroll
    for (int r = 0; r < 4; ++r) {
      int rloc = qd * 4 + r;
      int i = i0 + rloc;
      float srel;
      if (j <= i)          srel = bf2f(qp[rloc][1023 - i + j]);
      else if (j == i + 1) srel = 0.f;
      else                 srel = bf2f(qp[rloc + 1][j - i - 2]);
      sfr[f][r] = (sfr[f][r] + srel) * 0.125f;
    }
  }

  // ---- row max
  {
    float vm[4];
#pragma unroll
    for (int r = 0; r < 4; ++r) {
      float m = sfr[0][r];
#pragma unroll
      for (int f = 1; f < 16; ++f) m = fmaxf(m, sfr[f][r]);
#pragma unroll
      for (int off = 1; off < 16; off <<= 1) m = fmaxf(m, __shfl_xor(m, off, 64));
      vm[r] = m;
    }
    if (ln == 0) {
#pragma unroll
      for (int r = 0; r < 4; ++r) stats[0][w][qd * 4 + r] = vm[r];
    }
  }
  __syncthreads();   // stats ready; all qp(QEr) reads done -> safe to overwrite as P
  float gm[4];
#pragma unroll
  for (int r = 0; r < 4; ++r) {
    float m = stats[0][0][qd * 4 + r];
    m = fmaxf(m, stats[0][1][qd * 4 + r]);
    m = fmaxf(m, stats[0][2][qd * 4 + r]);
    m = fmaxf(m, stats[0][3][qd * 4 + r]);
    gm[r] = m;
  }

  // ---- exp, row sum, write P (unnormalized) into qp alias
  float vs[4] = {0.f, 0.f, 0.f, 0.f};
#pragma unroll
  for (int f = 0; f < 16; ++f) {
    int j = (f >> 2) * 256 + (((f & 3) * 4 + w) << 4) + ln;
#pragma unroll
    for (int r = 0; r < 4; ++r) {
      float e = __expf(sfr[f][r] - gm[r]);
      vs[r] += e;
      qp[qd * 4 + r][j] = f2bf(e);
    }
  }
#pragma unroll
  for (int r = 0; r < 4; ++r) {
    float s = vs[r];
#pragma unroll
    for (int off = 1; off < 16; off <<= 1) s += __shfl_xor(s, off, 64);
    if (ln == 0) stats[1][w][qd * 4 + r] = s;
  }
  __syncthreads();   // P + sums ready
  float rrl[4];
#pragma unroll
  for (int r = 0; r < 4; ++r) {
    float s = stats[1][0][qd * 4 + r] + stats[1][1][qd * 4 + r] +
              stats[1][2][qd * 4 + r] + stats[1][3][qd * 4 + r];
    rrl[r] = 1.0f / s;
  }

  // ---- phase 3: O = P @ v  (VT[dd][l] -> vectorized B-frag loads)
  f32x4 oacc = {0.f, 0.f, 0.f, 0.f};
  const ushort* vrow = vT + (size_t)(w * 16 + ln) * 1024;
#pragma unroll 4
  for (int ks = 0; ks < 32; ++ks) {
    bf16x8 ap = *(const bf16x8*)(&qp[ln][ks * 32 + qd * 8]);
    bf16x8 bv = *(const bf16x8*)(vrow + ks * 32 + qd * 8);
    oacc = __builtin_amdgcn_mfma_f32_16x16x32_bf16(ap, bv, oacc, 0, 0, 0);
  }

  // ---- store merged-head layout O[b][row][h*64 + dd]
  const int b = bh >> 4, h = bh & 15;
  ushort* ob = Om + ((size_t)b * L_ * D_) + (size_t)h * DH + (size_t)(w * 16 + ln);
#pragma unroll
  for (int r = 0; r < 4; ++r) {
    int row = i0 + qd * 4 + r;
    ob[(size_t)row * D_] = f2bf(oacc[r] * rrl[r]);
  }
}

extern "C" void kernel_launch(void* const* d_in, const int* in_sizes, int n_in,
                              void* d_out, int out_size, void* d_ws, size_t ws_size,
                              hipStream_t stream) {
  const float* query = (const float*)d_in[0];
  const float* key   = (const float*)d_in[1];
  const float* value = (const float*)d_in[2];
  const float* WQ    = (const float*)d_in[3];
  const float* WK    = (const float*)d_in[4];
  const float* WV    = (const float*)d_in[5];
  const float* Er    = (const float*)d_in[6];
  const float* WM    = (const float*)d_in[7];
  float* out = (float*)d_out;

  // workspace layout (ushorts): QW,KT,VT,O (4M each) + Erb (64K) + 4 WT (1M each) ~= 42.1 MB
  ushort* QW  = (ushort*)d_ws;
  ushort* KT  = QW  + (size_t)4096 * 1024;
  ushort* VT  = KT  + (size_t)4096 * 1024;
  ushort* O   = VT  + (size_t)4096 * 1024;
  ushort* Erb = O   + (size_t)4096 * 1024;
  ushort* WTQ = Erb + (size_t)65536;
  ushort* WTK = WTQ + (size_t)1024 * 1024;
  ushort* WTV = WTK + (size_t)1024 * 1024;
  ushort* WTM = WTV + (size_t)1024 * 1024;

  dim3 tg(16, 16);
  wT_kernel<<<tg, 256, 0, stream>>>(WQ, WTQ);
  wT_kernel<<<tg, 256, 0, stream>>>(WK, WTK);
  wT_kernel<<<tg, 256, 0, stream>>>(WV, WTV);
  wT_kernel<<<tg, 256, 0, stream>>>(WM, WTM);
  cvt_bf16_kernel<<<256, 256, 0, stream>>>(Er, Erb, L_ * DH);

  dim3 gg(8, 32);   // N/128, M/128
  gemm_kernel<true, OUT_BF16><<<gg, 256, 0, stream>>>(query, WTQ, QW);
  gemm_kernel<true, OUT_KT  ><<<gg, 256, 0, stream>>>(key,   WTK, KT);
  gemm_kernel<true, OUT_VT  ><<<gg, 256, 0, stream>>>(value, WTV, VT);

  attn_kernel<<<dim3(64, 64), 256, 0, stream>>>(QW, KT, VT, Erb, O);

  gemm_kernel<false, OUT_F32><<<gg, 256, 0, stream>>>(O, WTM, out);
}

// Round 3
// 445.945 us; speedup vs baseline: 1.3746x; 1.2673x over previous
//
#include <hip/hip_runtime.h>

#define H_  16
#define L_  1024
#define D_  1024
#define DH  64

typedef short bf16x8 __attribute__((ext_vector_type(8)));
typedef float f32x4  __attribute__((ext_vector_type(4)));

__device__ __forceinline__ ushort f2bf(float f) {
  union { float f; unsigned int u; } x; x.f = f;
  unsigned int u = x.u;
  u = (u + 0x7fffu + ((u >> 16) & 1u)) >> 16;   // RNE
  return (ushort)u;
}
__device__ __forceinline__ float bf2f(ushort s) {
  union { unsigned int u; float f; } x; x.u = ((unsigned int)s) << 16;
  return x.f;
}

__global__ __launch_bounds__(256) void cvt_bf16_kernel(const float* __restrict__ in,
                                                       ushort* __restrict__ out, int n) {
  int i = blockIdx.x * 256 + threadIdx.x;
  if (i < n) out[i] = f2bf(in[i]);
}

// W fp32 [1024][1024] row-major -> WT bf16 [n][k] (transposed)
__global__ __launch_bounds__(256) void wT_kernel(const float* __restrict__ W,
                                                 ushort* __restrict__ WT) {
  __shared__ ushort tt[64][72];
  const int t = threadIdx.x;
  const int k0 = blockIdx.y * 64, n0 = blockIdx.x * 64;
#pragma unroll
  for (int c = 0; c < 4; ++c) {
    int k = c * 16 + (t >> 4);
    float4 f = *(const float4*)(W + (size_t)(k0 + k) * 1024 + n0 + (t & 15) * 4);
    tt[(t & 15) * 4 + 0][k] = f2bf(f.x);
    tt[(t & 15) * 4 + 1][k] = f2bf(f.y);
    tt[(t & 15) * 4 + 2][k] = f2bf(f.z);
    tt[(t & 15) * 4 + 3][k] = f2bf(f.w);
  }
  __syncthreads();
#pragma unroll
  for (int p = 0; p < 2; ++p) {
    int n = p * 32 + (t >> 3);
    *(uint4*)(WT + (size_t)(n0 + n) * 1024 + k0 + (t & 7) * 8) = *(const uint4*)(&tt[n][(t & 7) * 8]);
  }
}

#define OUT_BF16 0
#define OUT_KT   1
#define OUT_VT   2
#define OUT_F32  3

// C[4096x1024] = A[4096x1024] @ B[1024x1024]; A fp32 or bf16; B passed as bf16 BT[n][k].
template<bool AF32, int OMODE>
__global__ __launch_bounds__(256) void gemm_kernel(const void* __restrict__ Ap,
                                                   const ushort* __restrict__ BT,
                                                   void* __restrict__ Cp) {
  __shared__ ushort lsA[128][40];   // [row][k], pad 40
  __shared__ ushort lsB[128][40];   // [n][k], pad 40
  const int tid  = threadIdx.x;
  const int w    = tid >> 6, lane = tid & 63, qd = lane >> 4, ln = lane & 15;
  const int rw   = w >> 1, cw = w & 1;
  const int m0   = blockIdx.y * 128, n0 = blockIdx.x * 128;

  f32x4 acc[16];
#pragma unroll
  for (int i = 0; i < 16; ++i) acc[i] = (f32x4){0.f, 0.f, 0.f, 0.f};

  for (int kb = 0; kb < 32; ++kb) {
    const int k0 = kb * 32;
    // ---- stage A tile [128 x 32] -> bf16 LDS
    {
      int row = tid >> 1, half = tid & 1;
      if (AF32) {
        const float* A = (const float*)Ap;
#pragma unroll
        for (int c = 0; c < 4; ++c) {
          float4 f = *(const float4*)(A + (size_t)(m0 + row) * 1024 + k0 + half * 16 + c * 4);
          ushort4 u;
          u.x = f2bf(f.x); u.y = f2bf(f.y); u.z = f2bf(f.z); u.w = f2bf(f.w);
          *(ushort4*)(&lsA[row][half * 16 + c * 4]) = u;
        }
      } else {
        const ushort* A = (const ushort*)Ap;
#pragma unroll
        for (int c = 0; c < 2; ++c) {
          uint4 u = *(const uint4*)(A + (size_t)(m0 + row) * 1024 + k0 + half * 16 + c * 8);
          *(uint4*)(&lsA[row][half * 16 + c * 8]) = u;
        }
      }
    }
    // ---- stage B tile: BT[n][k] bf16, vectorized copy
    {
      int row = tid >> 1, half = tid & 1;
#pragma unroll
      for (int c = 0; c < 2; ++c)
        *(uint4*)(&lsB[row][half * 16 + c * 8]) =
            *(const uint4*)(BT + (size_t)(n0 + row) * 1024 + k0 + half * 16 + c * 8);
    }
    __syncthreads();
    // ---- compute: wave tile 64x64 = 4x4 frags of 16x16
    bf16x8 afr[4], bfr[4];
#pragma unroll
    for (int am = 0; am < 4; ++am)
      afr[am] = *(const bf16x8*)(&lsA[rw * 64 + am * 16 + ln][qd * 8]);
#pragma unroll
    for (int bn = 0; bn < 4; ++bn)
      bfr[bn] = *(const bf16x8*)(&lsB[cw * 64 + bn * 16 + ln][qd * 8]);
#pragma unroll
    for (int am = 0; am < 4; ++am)
#pragma unroll
      for (int bn = 0; bn < 4; ++bn)
        acc[am * 4 + bn] = __builtin_amdgcn_mfma_f32_16x16x32_bf16(afr[am], bfr[bn], acc[am * 4 + bn], 0, 0, 0);
    __syncthreads();
  }
  // ---- epilogue
#pragma unroll
  for (int am = 0; am < 4; ++am)
#pragma unroll
    for (int bn = 0; bn < 4; ++bn) {
      const int rbase = m0 + rw * 64 + am * 16 + qd * 4;       // + r
      const int colg  = n0 + cw * 64 + bn * 16 + ln;
      if (OMODE == OUT_F32) {
#pragma unroll
        for (int r = 0; r < 4; ++r)
          ((float*)Cp)[(size_t)(rbase + r) * 1024 + colg] = acc[am * 4 + bn][r];
      } else if (OMODE == OUT_BF16) {
#pragma unroll
        for (int r = 0; r < 4; ++r)
          ((ushort*)Cp)[(size_t)(rbase + r) * 1024 + colg] = f2bf(acc[am * 4 + bn][r]);
      } else if (OMODE == OUT_KT) {
        // kT slab [64][1024] transposed -> KT[j][ki] at bh*65536 + j*64 + ki
        const int bh = rbase >> 6;
        const int ki = rbase & 63;                              // + r (contiguous)
        ushort4 u;
        u.x = f2bf(acc[am * 4 + bn][0]); u.y = f2bf(acc[am * 4 + bn][1]);
        u.z = f2bf(acc[am * 4 + bn][2]); u.w = f2bf(acc[am * 4 + bn][3]);
        *(ushort4*)((ushort*)Cp + (size_t)bh * 65536 + (size_t)colg * 64 + ki) = u;
      } else { // OUT_VT: v slab [1024][64] transposed -> VT[ki][lv] at bh*65536 + ki*1024 + lv
        const int bh = rbase >> 6;
#pragma unroll
        for (int r = 0; r < 4; ++r) {
          int lv = ((rbase + r) & 63) * 16 + (colg >> 6);
          int ki = colg & 63;
          ((ushort*)Cp)[(size_t)bh * 65536 + (size_t)ki * 1024 + lv] = f2bf(acc[am * 4 + bn][r]);
        }
      }
    }
}

// Fused relative attention. One workgroup = one (b,h) slab and a 16-row Q tile.
// q slab [1024][64]; KT[j=1024][k=64]; VT[dd=64][l=1024]; Er[m=1024][k=64].
// All global reads are coalesced into wave-private LDS staging regions; MFMA
// B-fragments come from LDS with conflict-free (2-way max) padded strides.
__global__ __launch_bounds__(256) void attn_kernel(
    const ushort* __restrict__ QW, const ushort* __restrict__ KTg,
    const ushort* __restrict__ VTg, const ushort* __restrict__ Erb,
    ushort* __restrict__ Om) {
  __shared__ ushort lq[32][72];     // q rows i0..i0+31 (clamped)
  __shared__ ushort qp[17][1032];   // QEr rows; later aliased as P[16][1024]
  __shared__ ushort stg[4][4608];   // per-wave staging: 64 rows x 72 (Er/KT) or 16 x 264 (VT)
  __shared__ float  stats[2][4][16];

  const int tid = threadIdx.x;
  const int w    = tid >> 6;
  const int lane = tid & 63;
  const int qd   = lane >> 4;
  const int ln   = lane & 15;
  const int bh   = blockIdx.y;
  const int i0   = blockIdx.x << 4;
  const ushort* q  = QW  + ((size_t)bh << 16);
  const ushort* kT = KTg + ((size_t)bh << 16);
  const ushort* vT = VTg + ((size_t)bh << 16);
  ushort* myst = &stg[w][0];

  { // stage q rows i0..i0+31 (coalesced)
    int r = tid >> 3;
    int c = (tid & 7) << 3;
    int row = i0 + r; if (row > L_ - 1) row = L_ - 1;
    *(uint4*)(&lq[r][c]) = *(const uint4*)(q + (size_t)row * DH + c);
  }
  __syncthreads();

  // A-fragments (q rows), loaded once
  bf16x8 a00 = *(const bf16x8*)(&lq[ln][qd * 8]);
  bf16x8 a01 = *(const bf16x8*)(&lq[ln][32 + qd * 8]);
  bf16x8 a10 = *(const bf16x8*)(&lq[16 + ln][qd * 8]);
  bf16x8 a11 = *(const bf16x8*)(&lq[16 + ln][32 + qd * 8]);

  const int jbase = w * 256;        // wave-owned contiguous column range
  const int strow = (lane >> 3) * 72 + (lane & 7) * 8;   // staging write slot (64x72 layout)

  // ---- phase 0: QEr cols [jbase, jbase+256) for rows i0..i0+16 -> qp
  {
    uint4 reg[8];
    const ushort* src = Erb + (size_t)jbase * 64;
#pragma unroll
    for (int t = 0; t < 8; ++t) reg[t] = *(const uint4*)(src + (t * 64 + lane) * 8);
    for (int c = 0; c < 4; ++c) {
#pragma unroll
      for (int t = 0; t < 8; ++t) *(uint4*)(myst + t * 8 * 72 + strow) = reg[t];
      if (c < 3) {
        const ushort* s2 = Erb + (size_t)(jbase + (c + 1) * 64) * 64;
#pragma unroll
        for (int t = 0; t < 8; ++t) reg[t] = *(const uint4*)(s2 + (t * 64 + lane) * 8);
      }
#pragma unroll
      for (int fi = 0; fi < 4; ++fi) {
        const int mb = jbase + c * 64 + fi * 16;
        bf16x8 b0 = *(const bf16x8*)(myst + (fi * 16 + ln) * 72 + qd * 8);
        bf16x8 b1 = *(const bf16x8*)(myst + (fi * 16 + ln) * 72 + 32 + qd * 8);
        f32x4 acc = {0.f, 0.f, 0.f, 0.f};
        acc = __builtin_amdgcn_mfma_f32_16x16x32_bf16(a00, b0, acc, 0, 0, 0);
        acc = __builtin_amdgcn_mfma_f32_16x16x32_bf16(a01, b1, acc, 0, 0, 0);
        const int m = mb + ln;
#pragma unroll
        for (int r = 0; r < 4; ++r) qp[qd * 4 + r][m] = f2bf(acc[r]);
        if (mb <= 1006 - i0) {   // row i0+16: only prefix columns are ever read
          f32x4 ac2 = {0.f, 0.f, 0.f, 0.f};
          ac2 = __builtin_amdgcn_mfma_f32_16x16x32_bf16(a10, b0, ac2, 0, 0, 0);
          ac2 = __builtin_amdgcn_mfma_f32_16x16x32_bf16(a11, b1, ac2, 0, 0, 0);
          if (qd == 0) qp[16][m] = f2bf(ac2[0]);
        }
      }
    }
  }
  __syncthreads();   // qp complete (skew reads cross wave column ranges)

  // ---- phase 1: S = q @ kT for cols [jbase, jbase+256)
  f32x4 sfr[16];
  {
    uint4 reg[8];
    const ushort* src = kT + (size_t)jbase * 64;
#pragma unroll
    for (int t = 0; t < 8; ++t) reg[t] = *(const uint4*)(src + (t * 64 + lane) * 8);
    for (int c = 0; c < 4; ++c) {
#pragma unroll
      for (int t = 0; t < 8; ++t) *(uint4*)(myst + t * 8 * 72 + strow) = reg[t];
      if (c < 3) {
        const ushort* s2 = kT + (size_t)(jbase + (c + 1) * 64) * 64;
#pragma unroll
        for (int t = 0; t < 8; ++t) reg[t] = *(const uint4*)(s2 + (t * 64 + lane) * 8);
      }
#pragma unroll
      for (int fi = 0; fi < 4; ++fi) {
        bf16x8 b0 = *(const bf16x8*)(myst + (fi * 16 + ln) * 72 + qd * 8);
        bf16x8 b1 = *(const bf16x8*)(myst + (fi * 16 + ln) * 72 + 32 + qd * 8);
        f32x4 acc = {0.f, 0.f, 0.f, 0.f};
        acc = __builtin_amdgcn_mfma_f32_16x16x32_bf16(a00, b0, acc, 0, 0, 0);
        acc = __builtin_amdgcn_mfma_f32_16x16x32_bf16(a01, b1, acc, 0, 0, 0);
        sfr[c * 4 + fi] = acc;
      }
    }
  }

  // ---- skew-add Srel + scale 1/sqrt(64)
#pragma unroll
  for (int f = 0; f < 16; ++f) {
    const int j = jbase + f * 16 + ln;
#pragma unroll
    for (int r = 0; r < 4; ++r) {
      int rloc = qd * 4 + r;
      int i = i0 + rloc;
      float srel;
      if (j <= i)          srel = bf2f(qp[rloc][1023 - i + j]);
      else if (j == i + 1) srel = 0.f;
      else                 srel = bf2f(qp[rloc + 1][j - i - 2]);
      sfr[f][r] = (sfr[f][r] + srel) * 0.125f;
    }
  }

  // ---- row max
  {
    float vm[4];
#pragma unroll
    for (int r = 0; r < 4; ++r) {
      float m = sfr[0][r];
#pragma unroll
      for (int f = 1; f < 16; ++f) m = fmaxf(m, sfr[f][r]);
#pragma unroll
      for (int off = 1; off < 16; off <<= 1) m = fmaxf(m, __shfl_xor(m, off, 64));
      vm[r] = m;
    }
    if (ln == 0) {
#pragma unroll
      for (int r = 0; r < 4; ++r) stats[0][w][qd * 4 + r] = vm[r];
    }
  }
  __syncthreads();   // stats ready; all qp(QEr) reads done -> safe to overwrite as P
  float gm[4];
#pragma unroll
  for (int r = 0; r < 4; ++r) {
    float m = stats[0][0][qd * 4 + r];
    m = fmaxf(m, stats[0][1][qd * 4 + r]);
    m = fmaxf(m, stats[0][2][qd * 4 + r]);
    m = fmaxf(m, stats[0][3][qd * 4 + r]);
    gm[r] = m;
  }

  // ---- exp, row sum, write P (unnormalized) into qp alias
  float vs[4] = {0.f, 0.f, 0.f, 0.f};
#pragma unroll
  for (int f = 0; f < 16; ++f) {
    const int j = jbase + f * 16 + ln;
#pragma unroll
    for (int r = 0; r < 4; ++r) {
      float e = __expf(sfr[f][r] - gm[r]);
      vs[r] += e;
      qp[qd * 4 + r][j] = f2bf(e);
    }
  }
#pragma unroll
  for (int r = 0; r < 4; ++r) {
    float s = vs[r];
#pragma unroll
    for (int off = 1; off < 16; off <<= 1) s += __shfl_xor(s, off, 64);
    if (ln == 0) stats[1][w][qd * 4 + r] = s;
  }
  __syncthreads();   // P + sums ready
  float rrl[4];
#pragma unroll
  for (int r = 0; r < 4; ++r) {
    float s = stats[1][0][qd * 4 + r] + stats[1][1][qd * 4 + r] +
              stats[1][2][qd * 4 + r] + stats[1][3][qd * 4 + r];
    rrl[r] = 1.0f / s;
  }

  // ---- phase 3: O = P @ v. Wave w owns dd in [w*16, w*16+16); stage VT rows into LDS.
  f32x4 oacc = {0.f, 0.f, 0.f, 0.f};
  {
    uint4 reg[8];
    const int id = lane;                 // 16B chunk id within (t,lane)
#pragma unroll
    for (int t = 0; t < 8; ++t) {
      int cid = t * 64 + id, dd = cid >> 5, lc = (cid & 31) * 8;
      reg[t] = *(const uint4*)(vT + (size_t)(w * 16 + dd) * 1024 + lc);
    }
    for (int c = 0; c < 4; ++c) {
#pragma unroll
      for (int t = 0; t < 8; ++t) {
        int cid = t * 64 + id, dd = cid >> 5, lc = (cid & 31) * 8;
        *(uint4*)(myst + dd * 264 + lc) = reg[t];
      }
      if (c < 3) {
#pragma unroll
        for (int t = 0; t < 8; ++t) {
          int cid = t * 64 + id, dd = cid >> 5, lc = (cid & 31) * 8;
          reg[t] = *(const uint4*)(vT + (size_t)(w * 16 + dd) * 1024 + (c + 1) * 256 + lc);
        }
      }
#pragma unroll
      for (int kl = 0; kl < 8; ++kl) {
        const int ks = c * 8 + kl;
        bf16x8 ap = *(const bf16x8*)(&qp[ln][ks * 32 + qd * 8]);
        bf16x8 bv = *(const bf16x8*)(myst + ln * 264 + kl * 32 + qd * 8);
        oacc = __builtin_amdgcn_mfma_f32_16x16x32_bf16(ap, bv, oacc, 0, 0, 0);
      }
    }
  }

  // ---- store merged-head layout O[b][row][h*64 + dd]
  const int b = bh >> 4, h = bh & 15;
  ushort* ob = Om + ((size_t)b * L_ * D_) + (size_t)h * DH + (size_t)(w * 16 + ln);
#pragma unroll
  for (int r = 0; r < 4; ++r) {
    int row = i0 + qd * 4 + r;
    ob[(size_t)row * D_] = f2bf(oacc[r] * rrl[r]);
  }
}

extern "C" void kernel_launch(void* const* d_in, const int* in_sizes, int n_in,
                              void* d_out, int out_size, void* d_ws, size_t ws_size,
                              hipStream_t stream) {
  const float* query = (const float*)d_in[0];
  const float* key   = (const float*)d_in[1];
  const float* value = (const float*)d_in[2];
  const float* WQ    = (const float*)d_in[3];
  const float* WK    = (const float*)d_in[4];
  const float* WV    = (const float*)d_in[5];
  const float* Er    = (const float*)d_in[6];
  const float* WM    = (const float*)d_in[7];
  float* out = (float*)d_out;

  // workspace layout (ushorts): QW,KT,VT,O (4M each) + Erb (64K) + 4 WT (1M each) ~= 42.1 MB
  ushort* QW  = (ushort*)d_ws;
  ushort* KT  = QW  + (size_t)4096 * 1024;
  ushort* VT  = KT  + (size_t)4096 * 1024;
  ushort* O   = VT  + (size_t)4096 * 1024;
  ushort* Erb = O   + (size_t)4096 * 1024;
  ushort* WTQ = Erb + (size_t)65536;
  ushort* WTK = WTQ + (size_t)1024 * 1024;
  ushort* WTV = WTK + (size_t)1024 * 1024;
  ushort* WTM = WTV + (size_t)1024 * 1024;

  dim3 tg(16, 16);
  wT_kernel<<<tg, 256, 0, stream>>>(WQ, WTQ);
  wT_kernel<<<tg, 256, 0, stream>>>(WK, WTK);
  wT_kernel<<<tg, 256, 0, stream>>>(WV, WTV);
  wT_kernel<<<tg, 256, 0, stream>>>(WM, WTM);
  cvt_bf16_kernel<<<256, 256, 0, stream>>>(Er, Erb, L_ * DH);

  dim3 gg(8, 32);   // N/128, M/128
  gemm_kernel<true, OUT_BF16><<<gg, 256, 0, stream>>>(query, WTQ, QW);
  gemm_kernel<true, OUT_KT  ><<<gg, 256, 0, stream>>>(key,   WTK, KT);
  gemm_kernel<true, OUT_VT  ><<<gg, 256, 0, stream>>>(value, WTV, VT);

  attn_kernel<<<dim3(64, 64), 256, 0, stream>>>(QW, KT, VT, Erb, O);

  gemm_kernel<false, OUT_F32><<<gg, 256, 0, stream>>>(O, WTM, out);
}

// Round 4
// 370.321 us; speedup vs baseline: 1.6553x; 1.2042x over previous
//
#include <hip/hip_runtime.h>

#define H_  16
#define L_  1024
#define D_  1024
#define DH  64

typedef short bf16x8 __attribute__((ext_vector_type(8)));
typedef float f32x4  __attribute__((ext_vector_type(4)));

__device__ __forceinline__ ushort f2bf(float f) {
  union { float f; unsigned int u; } x; x.f = f;
  unsigned int u = x.u;
  u = (u + 0x7fffu + ((u >> 16) & 1u)) >> 16;   // RNE
  return (ushort)u;
}
__device__ __forceinline__ float bf2f(ushort s) {
  union { unsigned int u; float f; } x; x.u = ((unsigned int)s) << 16;
  return x.f;
}

__global__ __launch_bounds__(256) void cvt_bf16_kernel(const float* __restrict__ in,
                                                       ushort* __restrict__ out, int n) {
  int i = blockIdx.x * 256 + threadIdx.x;
  if (i < n) out[i] = f2bf(in[i]);
}

// W fp32 [1024][1024] row-major -> WT bf16 [n][k] (transposed)
__global__ __launch_bounds__(256) void wT_kernel(const float* __restrict__ W,
                                                 ushort* __restrict__ WT) {
  __shared__ ushort tt[64][72];
  const int t = threadIdx.x;
  const int k0 = blockIdx.y * 64, n0 = blockIdx.x * 64;
#pragma unroll
  for (int c = 0; c < 4; ++c) {
    int k = c * 16 + (t >> 4);
    float4 f = *(const float4*)(W + (size_t)(k0 + k) * 1024 + n0 + (t & 15) * 4);
    tt[(t & 15) * 4 + 0][k] = f2bf(f.x);
    tt[(t & 15) * 4 + 1][k] = f2bf(f.y);
    tt[(t & 15) * 4 + 2][k] = f2bf(f.z);
    tt[(t & 15) * 4 + 3][k] = f2bf(f.w);
  }
  __syncthreads();
#pragma unroll
  for (int p = 0; p < 2; ++p) {
    int n = p * 32 + (t >> 3);
    *(uint4*)(WT + (size_t)(n0 + n) * 1024 + k0 + (t & 7) * 8) = *(const uint4*)(&tt[n][(t & 7) * 8]);
  }
}

// Fused Q/K/V projection GEMM: grid (8, 32, 3). z selects input, weight, and output layout.
// z=0: C bf16 row-major; z=1: KT[j][ki]; z=2: VT[ki][lv].
__global__ __launch_bounds__(256) void gemm_qkv_kernel(
    const float* __restrict__ Aq, const float* __restrict__ Ak, const float* __restrict__ Av,
    const ushort* __restrict__ BTq, const ushort* __restrict__ BTk, const ushort* __restrict__ BTv,
    ushort* __restrict__ Cq, ushort* __restrict__ Ck, ushort* __restrict__ Cv) {
  __shared__ ushort lsA[128][40];
  __shared__ ushort lsB[128][40];
  const int z = blockIdx.z;
  const float*  A  = (z == 0) ? Aq  : (z == 1) ? Ak  : Av;
  const ushort* BT = (z == 0) ? BTq : (z == 1) ? BTk : BTv;
  ushort*       Cp = (z == 0) ? Cq  : (z == 1) ? Ck  : Cv;

  const int tid  = threadIdx.x;
  const int w    = tid >> 6, lane = tid & 63, qd = lane >> 4, ln = lane & 15;
  const int rw   = w >> 1, cw = w & 1;
  const int m0   = blockIdx.y * 128, n0 = blockIdx.x * 128;

  f32x4 acc[16];
#pragma unroll
  for (int i = 0; i < 16; ++i) acc[i] = (f32x4){0.f, 0.f, 0.f, 0.f};

  for (int kb = 0; kb < 32; ++kb) {
    const int k0 = kb * 32;
    { // A tile [128 x 32] fp32 -> bf16 LDS
      int row = tid >> 1, half = tid & 1;
#pragma unroll
      for (int c = 0; c < 4; ++c) {
        float4 f = *(const float4*)(A + (size_t)(m0 + row) * 1024 + k0 + half * 16 + c * 4);
        ushort4 u;
        u.x = f2bf(f.x); u.y = f2bf(f.y); u.z = f2bf(f.z); u.w = f2bf(f.w);
        *(ushort4*)(&lsA[row][half * 16 + c * 4]) = u;
      }
    }
    { // B tile: BT[n][k] bf16 vector copy
      int row = tid >> 1, half = tid & 1;
#pragma unroll
      for (int c = 0; c < 2; ++c)
        *(uint4*)(&lsB[row][half * 16 + c * 8]) =
            *(const uint4*)(BT + (size_t)(n0 + row) * 1024 + k0 + half * 16 + c * 8);
    }
    __syncthreads();
    bf16x8 afr[4], bfr[4];
#pragma unroll
    for (int am = 0; am < 4; ++am)
      afr[am] = *(const bf16x8*)(&lsA[rw * 64 + am * 16 + ln][qd * 8]);
#pragma unroll
    for (int bn = 0; bn < 4; ++bn)
      bfr[bn] = *(const bf16x8*)(&lsB[cw * 64 + bn * 16 + ln][qd * 8]);
#pragma unroll
    for (int am = 0; am < 4; ++am)
#pragma unroll
      for (int bn = 0; bn < 4; ++bn)
        acc[am * 4 + bn] = __builtin_amdgcn_mfma_f32_16x16x32_bf16(afr[am], bfr[bn], acc[am * 4 + bn], 0, 0, 0);
    __syncthreads();
  }
#pragma unroll
  for (int am = 0; am < 4; ++am)
#pragma unroll
    for (int bn = 0; bn < 4; ++bn) {
      const int rbase = m0 + rw * 64 + am * 16 + qd * 4;
      const int colg  = n0 + cw * 64 + bn * 16 + ln;
      if (z == 0) {
#pragma unroll
        for (int r = 0; r < 4; ++r)
          Cp[(size_t)(rbase + r) * 1024 + colg] = f2bf(acc[am * 4 + bn][r]);
      } else if (z == 1) {
        const int bh = rbase >> 6;
        const int ki = rbase & 63;
        ushort4 u;
        u.x = f2bf(acc[am * 4 + bn][0]); u.y = f2bf(acc[am * 4 + bn][1]);
        u.z = f2bf(acc[am * 4 + bn][2]); u.w = f2bf(acc[am * 4 + bn][3]);
        *(ushort4*)(Cp + (size_t)bh * 65536 + (size_t)colg * 64 + ki) = u;
      } else {
        const int bh = rbase >> 6;
#pragma unroll
        for (int r = 0; r < 4; ++r) {
          int lv = ((rbase + r) & 63) * 16 + (colg >> 6);
          int ki = colg & 63;
          Cp[(size_t)bh * 65536 + (size_t)ki * 1024 + lv] = f2bf(acc[am * 4 + bn][r]);
        }
      }
    }
}

// Merge GEMM with in-block split-K: 512 threads / 8 waves. Waves 0-3 = K[0,512),
// waves 4-7 = K[512,1024); cross-half reduction through LDS; fp32 output.
__global__ __launch_bounds__(512) void gemm_mg_kernel(const ushort* __restrict__ A,
                                                      const ushort* __restrict__ BT,
                                                      float* __restrict__ Cp) {
  __shared__ ushort ls[2][2][128][40];   // [k-stream][A/B][row][col] = 40 KB
  const int tid  = threadIdx.x;
  const int w    = tid >> 6, lane = tid & 63, qd = lane >> 4, ln = lane & 15;
  const int kh   = w >> 2, q = w & 3;
  const int rw   = q >> 1, cw = q & 1;
  const int m0   = blockIdx.y * 128, n0 = blockIdx.x * 128;
  const int ts   = tid >> 8, tt = tid & 255;
  const int trow = tt >> 1, thalf = tt & 1;

  f32x4 acc[16];
#pragma unroll
  for (int i = 0; i < 16; ++i) acc[i] = (f32x4){0.f, 0.f, 0.f, 0.f};

  for (int kb = 0; kb < 16; ++kb) {
    const int k0 = ts * 512 + kb * 32;
#pragma unroll
    for (int c = 0; c < 2; ++c)
      *(uint4*)(&ls[ts][0][trow][thalf * 16 + c * 8]) =
          *(const uint4*)(A + (size_t)(m0 + trow) * 1024 + k0 + thalf * 16 + c * 8);
#pragma unroll
    for (int c = 0; c < 2; ++c)
      *(uint4*)(&ls[ts][1][trow][thalf * 16 + c * 8]) =
          *(const uint4*)(BT + (size_t)(n0 + trow) * 1024 + k0 + thalf * 16 + c * 8);
    __syncthreads();
    bf16x8 afr[4], bfr[4];
#pragma unroll
    for (int am = 0; am < 4; ++am)
      afr[am] = *(const bf16x8*)(&ls[kh][0][rw * 64 + am * 16 + ln][qd * 8]);
#pragma unroll
    for (int bn = 0; bn < 4; ++bn)
      bfr[bn] = *(const bf16x8*)(&ls[kh][1][cw * 64 + bn * 16 + ln][qd * 8]);
#pragma unroll
    for (int am = 0; am < 4; ++am)
#pragma unroll
      for (int bn = 0; bn < 4; ++bn)
        acc[am * 4 + bn] = __builtin_amdgcn_mfma_f32_16x16x32_bf16(afr[am], bfr[bn], acc[am * 4 + bn], 0, 0, 0);
    __syncthreads();
  }

  // cross-half reduction: waves 4-7 hand their 16 f32x4 to partner waves 0-3.
  // stride-33 fp32 layout -> conflict-free scalar b32 LDS ops. Two batches of 8 accs.
  float* red = (float*)&ls[0][0][0][0];   // 256 lanes * 33 floats = 33.8 KB <= 40 KB
  for (int half = 0; half < 2; ++half) {
    __syncthreads();
    if (w >= 4) {
      const int base = ((w - 4) * 64 + lane) * 33;
#pragma unroll
      for (int i = 0; i < 8; ++i)
#pragma unroll
        for (int c = 0; c < 4; ++c) red[base + i * 4 + c] = acc[half * 8 + i][c];
    }
    __syncthreads();
    if (w < 4) {
      const int base = (w * 64 + lane) * 33;
#pragma unroll
      for (int i = 0; i < 8; ++i)
#pragma unroll
        for (int c = 0; c < 4; ++c) acc[half * 8 + i][c] += red[base + i * 4 + c];
    }
  }
  if (w < 4) {
#pragma unroll
    for (int am = 0; am < 4; ++am)
#pragma unroll
      for (int bn = 0; bn < 4; ++bn) {
        const int rbase = m0 + rw * 64 + am * 16 + qd * 4;
        const int colg  = n0 + cw * 64 + bn * 16 + ln;
#pragma unroll
        for (int r = 0; r < 4; ++r)
          Cp[(size_t)(rbase + r) * 1024 + colg] = acc[am * 4 + bn][r];
      }
  }
}

// Fused relative attention (unchanged from round 3).
__global__ __launch_bounds__(256) void attn_kernel(
    const ushort* __restrict__ QW, const ushort* __restrict__ KTg,
    const ushort* __restrict__ VTg, const ushort* __restrict__ Erb,
    ushort* __restrict__ Om) {
  __shared__ ushort lq[32][72];
  __shared__ ushort qp[17][1032];
  __shared__ ushort stg[4][4608];
  __shared__ float  stats[2][4][16];

  const int tid = threadIdx.x;
  const int w    = tid >> 6;
  const int lane = tid & 63;
  const int qd   = lane >> 4;
  const int ln   = lane & 15;
  const int bh   = blockIdx.y;
  const int i0   = blockIdx.x << 4;
  const ushort* q  = QW  + ((size_t)bh << 16);
  const ushort* kT = KTg + ((size_t)bh << 16);
  const ushort* vT = VTg + ((size_t)bh << 16);
  ushort* myst = &stg[w][0];

  {
    int r = tid >> 3;
    int c = (tid & 7) << 3;
    int row = i0 + r; if (row > L_ - 1) row = L_ - 1;
    *(uint4*)(&lq[r][c]) = *(const uint4*)(q + (size_t)row * DH + c);
  }
  __syncthreads();

  bf16x8 a00 = *(const bf16x8*)(&lq[ln][qd * 8]);
  bf16x8 a01 = *(const bf16x8*)(&lq[ln][32 + qd * 8]);
  bf16x8 a10 = *(const bf16x8*)(&lq[16 + ln][qd * 8]);
  bf16x8 a11 = *(const bf16x8*)(&lq[16 + ln][32 + qd * 8]);

  const int jbase = w * 256;
  const int strow = (lane >> 3) * 72 + (lane & 7) * 8;

  // ---- phase 0: QEr
  {
    uint4 reg[8];
    const ushort* src = Erb + (size_t)jbase * 64;
#pragma unroll
    for (int t = 0; t < 8; ++t) reg[t] = *(const uint4*)(src + (t * 64 + lane) * 8);
    for (int c = 0; c < 4; ++c) {
#pragma unroll
      for (int t = 0; t < 8; ++t) *(uint4*)(myst + t * 8 * 72 + strow) = reg[t];
      if (c < 3) {
        const ushort* s2 = Erb + (size_t)(jbase + (c + 1) * 64) * 64;
#pragma unroll
        for (int t = 0; t < 8; ++t) reg[t] = *(const uint4*)(s2 + (t * 64 + lane) * 8);
      }
#pragma unroll
      for (int fi = 0; fi < 4; ++fi) {
        const int mb = jbase + c * 64 + fi * 16;
        bf16x8 b0 = *(const bf16x8*)(myst + (fi * 16 + ln) * 72 + qd * 8);
        bf16x8 b1 = *(const bf16x8*)(myst + (fi * 16 + ln) * 72 + 32 + qd * 8);
        f32x4 acc = {0.f, 0.f, 0.f, 0.f};
        acc = __builtin_amdgcn_mfma_f32_16x16x32_bf16(a00, b0, acc, 0, 0, 0);
        acc = __builtin_amdgcn_mfma_f32_16x16x32_bf16(a01, b1, acc, 0, 0, 0);
        const int m = mb + ln;
#pragma unroll
        for (int r = 0; r < 4; ++r) qp[qd * 4 + r][m] = f2bf(acc[r]);
        if (mb <= 1006 - i0) {
          f32x4 ac2 = {0.f, 0.f, 0.f, 0.f};
          ac2 = __builtin_amdgcn_mfma_f32_16x16x32_bf16(a10, b0, ac2, 0, 0, 0);
          ac2 = __builtin_amdgcn_mfma_f32_16x16x32_bf16(a11, b1, ac2, 0, 0, 0);
          if (qd == 0) qp[16][m] = f2bf(ac2[0]);
        }
      }
    }
  }
  __syncthreads();

  // ---- phase 1: S = q @ kT
  f32x4 sfr[16];
  {
    uint4 reg[8];
    const ushort* src = kT + (size_t)jbase * 64;
#pragma unroll
    for (int t = 0; t < 8; ++t) reg[t] = *(const uint4*)(src + (t * 64 + lane) * 8);
    for (int c = 0; c < 4; ++c) {
#pragma unroll
      for (int t = 0; t < 8; ++t) *(uint4*)(myst + t * 8 * 72 + strow) = reg[t];
      if (c < 3) {
        const ushort* s2 = kT + (size_t)(jbase + (c + 1) * 64) * 64;
#pragma unroll
        for (int t = 0; t < 8; ++t) reg[t] = *(const uint4*)(s2 + (t * 64 + lane) * 8);
      }
#pragma unroll
      for (int fi = 0; fi < 4; ++fi) {
        bf16x8 b0 = *(const bf16x8*)(myst + (fi * 16 + ln) * 72 + qd * 8);
        bf16x8 b1 = *(const bf16x8*)(myst + (fi * 16 + ln) * 72 + 32 + qd * 8);
        f32x4 acc = {0.f, 0.f, 0.f, 0.f};
        acc = __builtin_amdgcn_mfma_f32_16x16x32_bf16(a00, b0, acc, 0, 0, 0);
        acc = __builtin_amdgcn_mfma_f32_16x16x32_bf16(a01, b1, acc, 0, 0, 0);
        sfr[c * 4 + fi] = acc;
      }
    }
  }

#pragma unroll
  for (int f = 0; f < 16; ++f) {
    const int j = jbase + f * 16 + ln;
#pragma unroll
    for (int r = 0; r < 4; ++r) {
      int rloc = qd * 4 + r;
      int i = i0 + rloc;
      float srel;
      if (j <= i)          srel = bf2f(qp[rloc][1023 - i + j]);
      else if (j == i + 1) srel = 0.f;
      else                 srel = bf2f(qp[rloc + 1][j - i - 2]);
      sfr[f][r] = (sfr[f][r] + srel) * 0.125f;
    }
  }

  {
    float vm[4];
#pragma unroll
    for (int r = 0; r < 4; ++r) {
      float m = sfr[0][r];
#pragma unroll
      for (int f = 1; f < 16; ++f) m = fmaxf(m, sfr[f][r]);
#pragma unroll
      for (int off = 1; off < 16; off <<= 1) m = fmaxf(m, __shfl_xor(m, off, 64));
      vm[r] = m;
    }
    if (ln == 0) {
#pragma unroll
      for (int r = 0; r < 4; ++r) stats[0][w][qd * 4 + r] = vm[r];
    }
  }
  __syncthreads();
  float gm[4];
#pragma unroll
  for (int r = 0; r < 4; ++r) {
    float m = stats[0][0][qd * 4 + r];
    m = fmaxf(m, stats[0][1][qd * 4 + r]);
    m = fmaxf(m, stats[0][2][qd * 4 + r]);
    m = fmaxf(m, stats[0][3][qd * 4 + r]);
    gm[r] = m;
  }

  float vs[4] = {0.f, 0.f, 0.f, 0.f};
#pragma unroll
  for (int f = 0; f < 16; ++f) {
    const int j = jbase + f * 16 + ln;
#pragma unroll
    for (int r = 0; r < 4; ++r) {
      float e = __expf(sfr[f][r] - gm[r]);
      vs[r] += e;
      qp[qd * 4 + r][j] = f2bf(e);
    }
  }
#pragma unroll
  for (int r = 0; r < 4; ++r) {
    float s = vs[r];
#pragma unroll
    for (int off = 1; off < 16; off <<= 1) s += __shfl_xor(s, off, 64);
    if (ln == 0) stats[1][w][qd * 4 + r] = s;
  }
  __syncthreads();
  float rrl[4];
#pragma unroll
  for (int r = 0; r < 4; ++r) {
    float s = stats[1][0][qd * 4 + r] + stats[1][1][qd * 4 + r] +
              stats[1][2][qd * 4 + r] + stats[1][3][qd * 4 + r];
    rrl[r] = 1.0f / s;
  }

  f32x4 oacc = {0.f, 0.f, 0.f, 0.f};
  {
    uint4 reg[8];
    const int id = lane;
#pragma unroll
    for (int t = 0; t < 8; ++t) {
      int cid = t * 64 + id, dd = cid >> 5, lc = (cid & 31) * 8;
      reg[t] = *(const uint4*)(vT + (size_t)(w * 16 + dd) * 1024 + lc);
    }
    for (int c = 0; c < 4; ++c) {
#pragma unroll
      for (int t = 0; t < 8; ++t) {
        int cid = t * 64 + id, dd = cid >> 5, lc = (cid & 31) * 8;
        *(uint4*)(myst + dd * 264 + lc) = reg[t];
      }
      if (c < 3) {
#pragma unroll
        for (int t = 0; t < 8; ++t) {
          int cid = t * 64 + id, dd = cid >> 5, lc = (cid & 31) * 8;
          reg[t] = *(const uint4*)(vT + (size_t)(w * 16 + dd) * 1024 + (c + 1) * 256 + lc);
        }
      }
#pragma unroll
      for (int kl = 0; kl < 8; ++kl) {
        const int ks = c * 8 + kl;
        bf16x8 ap = *(const bf16x8*)(&qp[ln][ks * 32 + qd * 8]);
        bf16x8 bv = *(const bf16x8*)(myst + ln * 264 + kl * 32 + qd * 8);
        oacc = __builtin_amdgcn_mfma_f32_16x16x32_bf16(ap, bv, oacc, 0, 0, 0);
      }
    }
  }

  const int b = bh >> 4, h = bh & 15;
  ushort* ob = Om + ((size_t)b * L_ * D_) + (size_t)h * DH + (size_t)(w * 16 + ln);
#pragma unroll
  for (int r = 0; r < 4; ++r) {
    int row = i0 + qd * 4 + r;
    ob[(size_t)row * D_] = f2bf(oacc[r] * rrl[r]);
  }
}

extern "C" void kernel_launch(void* const* d_in, const int* in_sizes, int n_in,
                              void* d_out, int out_size, void* d_ws, size_t ws_size,
                              hipStream_t stream) {
  const float* query = (const float*)d_in[0];
  const float* key   = (const float*)d_in[1];
  const float* value = (const float*)d_in[2];
  const float* WQ    = (const float*)d_in[3];
  const float* WK    = (const float*)d_in[4];
  const float* WV    = (const float*)d_in[5];
  const float* Er    = (const float*)d_in[6];
  const float* WM    = (const float*)d_in[7];
  float* out = (float*)d_out;

  ushort* QW  = (ushort*)d_ws;
  ushort* KT  = QW  + (size_t)4096 * 1024;
  ushort* VT  = KT  + (size_t)4096 * 1024;
  ushort* O   = VT  + (size_t)4096 * 1024;
  ushort* Erb = O   + (size_t)4096 * 1024;
  ushort* WTQ = Erb + (size_t)65536;
  ushort* WTK = WTQ + (size_t)1024 * 1024;
  ushort* WTV = WTK + (size_t)1024 * 1024;
  ushort* WTM = WTV + (size_t)1024 * 1024;

  dim3 tg(16, 16);
  wT_kernel<<<tg, 256, 0, stream>>>(WQ, WTQ);
  wT_kernel<<<tg, 256, 0, stream>>>(WK, WTK);
  wT_kernel<<<tg, 256, 0, stream>>>(WV, WTV);
  wT_kernel<<<tg, 256, 0, stream>>>(WM, WTM);
  cvt_bf16_kernel<<<256, 256, 0, stream>>>(Er, Erb, L_ * DH);

  gemm_qkv_kernel<<<dim3(8, 32, 3), 256, 0, stream>>>(query, key, value,
                                                      WTQ, WTK, WTV,
                                                      QW, KT, VT);

  attn_kernel<<<dim3(64, 64), 256, 0, stream>>>(QW, KT, VT, Erb, O);

  gemm_mg_kernel<<<dim3(8, 32), 512, 0, stream>>>(O, WTM, out);
}

// Round 5
// 349.741 us; speedup vs baseline: 1.7527x; 1.0588x over previous
//
#include <hip/hip_runtime.h>

#define H_  16
#define L_  1024
#define D_  1024
#define DH  64

typedef short bf16x8 __attribute__((ext_vector_type(8)));
typedef float f32x4  __attribute__((ext_vector_type(4)));

__device__ __forceinline__ ushort f2bf(float f) {
  union { float f; unsigned int u; } x; x.f = f;
  unsigned int u = x.u;
  u = (u + 0x7fffu + ((u >> 16) & 1u)) >> 16;   // RNE
  return (ushort)u;
}
__device__ __forceinline__ float bf2f(ushort s) {
  union { unsigned int u; float f; } x; x.u = ((unsigned int)s) << 16;
  return x.f;
}

__global__ __launch_bounds__(256) void cvt_bf16_kernel(const float* __restrict__ in,
                                                       ushort* __restrict__ out, int n) {
  int i = blockIdx.x * 256 + threadIdx.x;
  if (i < n) out[i] = f2bf(in[i]);
}

// 4 weight transposes fused: W fp32 [1024][1024] -> WT bf16 [n][k]; z selects matrix.
__global__ __launch_bounds__(256) void wT4_kernel(
    const float* __restrict__ W0, const float* __restrict__ W1,
    const float* __restrict__ W2, const float* __restrict__ W3,
    ushort* __restrict__ T0, ushort* __restrict__ T1,
    ushort* __restrict__ T2, ushort* __restrict__ T3) {
  __shared__ ushort tt[64][72];
  const int z = blockIdx.z;
  const float* W = (z == 0) ? W0 : (z == 1) ? W1 : (z == 2) ? W2 : W3;
  ushort*     WT = (z == 0) ? T0 : (z == 1) ? T1 : (z == 2) ? T2 : T3;
  const int t = threadIdx.x;
  const int k0 = blockIdx.y * 64, n0 = blockIdx.x * 64;
#pragma unroll
  for (int c = 0; c < 4; ++c) {
    int k = c * 16 + (t >> 4);
    float4 f = *(const float4*)(W + (size_t)(k0 + k) * 1024 + n0 + (t & 15) * 4);
    tt[(t & 15) * 4 + 0][k] = f2bf(f.x);
    tt[(t & 15) * 4 + 1][k] = f2bf(f.y);
    tt[(t & 15) * 4 + 2][k] = f2bf(f.z);
    tt[(t & 15) * 4 + 3][k] = f2bf(f.w);
  }
  __syncthreads();
#pragma unroll
  for (int p = 0; p < 2; ++p) {
    int n = p * 32 + (t >> 3);
    *(uint4*)(WT + (size_t)(n0 + n) * 1024 + k0 + (t & 7) * 8) = *(const uint4*)(&tt[n][(t & 7) * 8]);
  }
}

// Fused Q/K/V projection GEMM: grid (8, 32, 3). z selects input, weight, and output layout.
__global__ __launch_bounds__(256) void gemm_qkv_kernel(
    const float* __restrict__ Aq, const float* __restrict__ Ak, const float* __restrict__ Av,
    const ushort* __restrict__ BTq, const ushort* __restrict__ BTk, const ushort* __restrict__ BTv,
    ushort* __restrict__ Cq, ushort* __restrict__ Ck, ushort* __restrict__ Cv) {
  __shared__ ushort lsA[128][40];
  __shared__ ushort lsB[128][40];
  const int z = blockIdx.z;
  const float*  A  = (z == 0) ? Aq  : (z == 1) ? Ak  : Av;
  const ushort* BT = (z == 0) ? BTq : (z == 1) ? BTk : BTv;
  ushort*       Cp = (z == 0) ? Cq  : (z == 1) ? Ck  : Cv;

  const int tid  = threadIdx.x;
  const int w    = tid >> 6, lane = tid & 63, qd = lane >> 4, ln = lane & 15;
  const int rw   = w >> 1, cw = w & 1;
  const int m0   = blockIdx.y * 128, n0 = blockIdx.x * 128;

  f32x4 acc[16];
#pragma unroll
  for (int i = 0; i < 16; ++i) acc[i] = (f32x4){0.f, 0.f, 0.f, 0.f};

  for (int kb = 0; kb < 32; ++kb) {
    const int k0 = kb * 32;
    {
      int row = tid >> 1, half = tid & 1;
#pragma unroll
      for (int c = 0; c < 4; ++c) {
        float4 f = *(const float4*)(A + (size_t)(m0 + row) * 1024 + k0 + half * 16 + c * 4);
        ushort4 u;
        u.x = f2bf(f.x); u.y = f2bf(f.y); u.z = f2bf(f.z); u.w = f2bf(f.w);
        *(ushort4*)(&lsA[row][half * 16 + c * 4]) = u;
      }
    }
    {
      int row = tid >> 1, half = tid & 1;
#pragma unroll
      for (int c = 0; c < 2; ++c)
        *(uint4*)(&lsB[row][half * 16 + c * 8]) =
            *(const uint4*)(BT + (size_t)(n0 + row) * 1024 + k0 + half * 16 + c * 8);
    }
    __syncthreads();
    bf16x8 afr[4], bfr[4];
#pragma unroll
    for (int am = 0; am < 4; ++am)
      afr[am] = *(const bf16x8*)(&lsA[rw * 64 + am * 16 + ln][qd * 8]);
#pragma unroll
    for (int bn = 0; bn < 4; ++bn)
      bfr[bn] = *(const bf16x8*)(&lsB[cw * 64 + bn * 16 + ln][qd * 8]);
#pragma unroll
    for (int am = 0; am < 4; ++am)
#pragma unroll
      for (int bn = 0; bn < 4; ++bn)
        acc[am * 4 + bn] = __builtin_amdgcn_mfma_f32_16x16x32_bf16(afr[am], bfr[bn], acc[am * 4 + bn], 0, 0, 0);
    __syncthreads();
  }
#pragma unroll
  for (int am = 0; am < 4; ++am)
#pragma unroll
    for (int bn = 0; bn < 4; ++bn) {
      const int rbase = m0 + rw * 64 + am * 16 + qd * 4;
      const int colg  = n0 + cw * 64 + bn * 16 + ln;
      if (z == 0) {
#pragma unroll
        for (int r = 0; r < 4; ++r)
          Cp[(size_t)(rbase + r) * 1024 + colg] = f2bf(acc[am * 4 + bn][r]);
      } else if (z == 1) {
        const int bh = rbase >> 6;
        const int ki = rbase & 63;
        ushort4 u;
        u.x = f2bf(acc[am * 4 + bn][0]); u.y = f2bf(acc[am * 4 + bn][1]);
        u.z = f2bf(acc[am * 4 + bn][2]); u.w = f2bf(acc[am * 4 + bn][3]);
        *(ushort4*)(Cp + (size_t)bh * 65536 + (size_t)colg * 64 + ki) = u;
      } else {
        const int bh = rbase >> 6;
#pragma unroll
        for (int r = 0; r < 4; ++r) {
          int lv = ((rbase + r) & 63) * 16 + (colg >> 6);
          int ki = colg & 63;
          Cp[(size_t)bh * 65536 + (size_t)ki * 1024 + lv] = f2bf(acc[am * 4 + bn][r]);
        }
      }
    }
}

// Merge GEMM with in-block split-K (unchanged).
__global__ __launch_bounds__(512) void gemm_mg_kernel(const ushort* __restrict__ A,
                                                      const ushort* __restrict__ BT,
                                                      float* __restrict__ Cp) {
  __shared__ ushort ls[2][2][128][40];
  const int tid  = threadIdx.x;
  const int w    = tid >> 6, lane = tid & 63, qd = lane >> 4, ln = lane & 15;
  const int kh   = w >> 2, q = w & 3;
  const int rw   = q >> 1, cw = q & 1;
  const int m0   = blockIdx.y * 128, n0 = blockIdx.x * 128;
  const int ts   = tid >> 8, tt = tid & 255;
  const int trow = tt >> 1, thalf = tt & 1;

  f32x4 acc[16];
#pragma unroll
  for (int i = 0; i < 16; ++i) acc[i] = (f32x4){0.f, 0.f, 0.f, 0.f};

  for (int kb = 0; kb < 16; ++kb) {
    const int k0 = ts * 512 + kb * 32;
#pragma unroll
    for (int c = 0; c < 2; ++c)
      *(uint4*)(&ls[ts][0][trow][thalf * 16 + c * 8]) =
          *(const uint4*)(A + (size_t)(m0 + trow) * 1024 + k0 + thalf * 16 + c * 8);
#pragma unroll
    for (int c = 0; c < 2; ++c)
      *(uint4*)(&ls[ts][1][trow][thalf * 16 + c * 8]) =
          *(const uint4*)(BT + (size_t)(n0 + trow) * 1024 + k0 + thalf * 16 + c * 8);
    __syncthreads();
    bf16x8 afr[4], bfr[4];
#pragma unroll
    for (int am = 0; am < 4; ++am)
      afr[am] = *(const bf16x8*)(&ls[kh][0][rw * 64 + am * 16 + ln][qd * 8]);
#pragma unroll
    for (int bn = 0; bn < 4; ++bn)
      bfr[bn] = *(const bf16x8*)(&ls[kh][1][cw * 64 + bn * 16 + ln][qd * 8]);
#pragma unroll
    for (int am = 0; am < 4; ++am)
#pragma unroll
      for (int bn = 0; bn < 4; ++bn)
        acc[am * 4 + bn] = __builtin_amdgcn_mfma_f32_16x16x32_bf16(afr[am], bfr[bn], acc[am * 4 + bn], 0, 0, 0);
    __syncthreads();
  }

  float* red = (float*)&ls[0][0][0][0];
  for (int half = 0; half < 2; ++half) {
    __syncthreads();
    if (w >= 4) {
      const int base = ((w - 4) * 64 + lane) * 33;
#pragma unroll
      for (int i = 0; i < 8; ++i)
#pragma unroll
        for (int c = 0; c < 4; ++c) red[base + i * 4 + c] = acc[half * 8 + i][c];
    }
    __syncthreads();
    if (w < 4) {
      const int base = (w * 64 + lane) * 33;
#pragma unroll
      for (int i = 0; i < 8; ++i)
#pragma unroll
        for (int c = 0; c < 4; ++c) acc[half * 8 + i][c] += red[base + i * 4 + c];
    }
  }
  if (w < 4) {
#pragma unroll
    for (int am = 0; am < 4; ++am)
#pragma unroll
      for (int bn = 0; bn < 4; ++bn) {
        const int rbase = m0 + rw * 64 + am * 16 + qd * 4;
        const int colg  = n0 + cw * 64 + bn * 16 + ln;
#pragma unroll
        for (int r = 0; r < 4; ++r)
          Cp[(size_t)(rbase + r) * 1024 + colg] = acc[am * 4 + bn][r];
      }
  }
}

// Fused relative attention, 512 threads / 8 waves. Block = (bh, 16 Q-rows).
// Wave w owns cols [w*128, w*128+128) for QEr/S/softmax; PV is split-K across wave pairs.
__global__ __launch_bounds__(512, 4) void attn_kernel(
    const ushort* __restrict__ QW, const ushort* __restrict__ KTg,
    const ushort* __restrict__ VTg, const ushort* __restrict__ Erb,
    ushort* __restrict__ Om) {
  __shared__ ushort lq[17][72];      // q rows i0..i0+16
  __shared__ ushort qp[17][1032];    // QEr rows; later aliased as P[16][1024]
  __shared__ ushort stg[8][2304];    // per-wave staging: 32x72 (Er/KT) / 16x136 (VT) / O-red
  __shared__ float  stats[2][8][16];

  const int tid  = threadIdx.x;
  const int w    = tid >> 6;
  const int lane = tid & 63;
  const int qd   = lane >> 4;
  const int ln   = lane & 15;
  const int bh   = blockIdx.y;
  const int i0   = blockIdx.x << 4;
  const ushort* q  = QW  + ((size_t)bh << 16);
  const ushort* kT = KTg + ((size_t)bh << 16);
  const ushort* vT = VTg + ((size_t)bh << 16);
  ushort* myst = &stg[w][0];

  if (tid < 272) {   // stage q rows i0..i0+16 (17 rows x 64), coalesced uint2
    int r = tid >> 4, c = (tid & 15) * 4;
    int row = i0 + r; if (row > 1023) row = 1023;
    *(uint2*)(&lq[r][c]) = *(const uint2*)(q + (size_t)row * DH + c);
  }
  __syncthreads();

  bf16x8 a00 = *(const bf16x8*)(&lq[ln][qd * 8]);
  bf16x8 a01 = *(const bf16x8*)(&lq[ln][32 + qd * 8]);
  bf16x8 a10 = *(const bf16x8*)(&lq[16][qd * 8]);       // broadcast row i0+16
  bf16x8 a11 = *(const bf16x8*)(&lq[16][32 + qd * 8]);  // (only output row 0 kept)

  const int jbase = w * 128;
  // staging ids: 32 rows x 64 ush = 256 uint4, 4 per lane
  int srow[4], sseg[4];
#pragma unroll
  for (int t = 0; t < 4; ++t) { int cid = t * 64 + lane; srow[t] = cid >> 3; sseg[t] = (cid & 7) * 8; }

  // ---- phase 0: QEr cols [jbase, jbase+128) -> qp rows 0..16
  {
    uint4 pre[4];
    const ushort* src = Erb + (size_t)jbase * 64;
#pragma unroll
    for (int t = 0; t < 4; ++t) pre[t] = *(const uint4*)(src + (t * 64 + lane) * 8);
    for (int c = 0; c < 4; ++c) {
#pragma unroll
      for (int t = 0; t < 4; ++t) *(uint4*)(myst + srow[t] * 72 + sseg[t]) = pre[t];
      if (c < 3) {
        const ushort* s2 = Erb + (size_t)(jbase + (c + 1) * 32) * 64;
#pragma unroll
        for (int t = 0; t < 4; ++t) pre[t] = *(const uint4*)(s2 + (t * 64 + lane) * 8);
      }
#pragma unroll
      for (int fi = 0; fi < 2; ++fi) {
        const int mb = jbase + c * 32 + fi * 16;
        bf16x8 b0 = *(const bf16x8*)(myst + (fi * 16 + ln) * 72 + qd * 8);
        bf16x8 b1 = *(const bf16x8*)(myst + (fi * 16 + ln) * 72 + 32 + qd * 8);
        f32x4 acc = {0.f, 0.f, 0.f, 0.f};
        acc = __builtin_amdgcn_mfma_f32_16x16x32_bf16(a00, b0, acc, 0, 0, 0);
        acc = __builtin_amdgcn_mfma_f32_16x16x32_bf16(a01, b1, acc, 0, 0, 0);
        const int m = mb + ln;
#pragma unroll
        for (int r = 0; r < 4; ++r) qp[qd * 4 + r][m] = f2bf(acc[r]);
        if (mb <= 1006 - i0) {   // row i0+16 prefix
          f32x4 ac2 = {0.f, 0.f, 0.f, 0.f};
          ac2 = __builtin_amdgcn_mfma_f32_16x16x32_bf16(a10, b0, ac2, 0, 0, 0);
          ac2 = __builtin_amdgcn_mfma_f32_16x16x32_bf16(a11, b1, ac2, 0, 0, 0);
          if (qd == 0) qp[16][m] = f2bf(ac2[0]);
        }
      }
    }
  }
  __syncthreads();   // qp complete (skew reads cross wave col ranges)

  // ---- phase 1: S = q @ kT for cols [jbase, jbase+128)
  f32x4 sfr[8];
  {
    uint4 pre[4];
    const ushort* src = kT + (size_t)jbase * 64;
#pragma unroll
    for (int t = 0; t < 4; ++t) pre[t] = *(const uint4*)(src + (t * 64 + lane) * 8);
    for (int c = 0; c < 4; ++c) {
#pragma unroll
      for (int t = 0; t < 4; ++t) *(uint4*)(myst + srow[t] * 72 + sseg[t]) = pre[t];
      if (c < 3) {
        const ushort* s2 = kT + (size_t)(jbase + (c + 1) * 32) * 64;
#pragma unroll
        for (int t = 0; t < 4; ++t) pre[t] = *(const uint4*)(s2 + (t * 64 + lane) * 8);
      }
#pragma unroll
      for (int fi = 0; fi < 2; ++fi) {
        bf16x8 b0 = *(const bf16x8*)(myst + (fi * 16 + ln) * 72 + qd * 8);
        bf16x8 b1 = *(const bf16x8*)(myst + (fi * 16 + ln) * 72 + 32 + qd * 8);
        f32x4 acc = {0.f, 0.f, 0.f, 0.f};
        acc = __builtin_amdgcn_mfma_f32_16x16x32_bf16(a00, b0, acc, 0, 0, 0);
        acc = __builtin_amdgcn_mfma_f32_16x16x32_bf16(a01, b1, acc, 0, 0, 0);
        sfr[c * 2 + fi] = acc;
      }
    }
  }

  // ---- skew-add Srel + scale 1/sqrt(64)
#pragma unroll
  for (int f = 0; f < 8; ++f) {
    const int j = jbase + f * 16 + ln;
#pragma unroll
    for (int r = 0; r < 4; ++r) {
      int rloc = qd * 4 + r;
      int i = i0 + rloc;
      float srel;
      if (j <= i)          srel = bf2f(qp[rloc][1023 - i + j]);
      else if (j == i + 1) srel = 0.f;
      else                 srel = bf2f(qp[rloc + 1][j - i - 2]);
      sfr[f][r] = (sfr[f][r] + srel) * 0.125f;
    }
  }

  // ---- row max
  {
    float vm[4];
#pragma unroll
    for (int r = 0; r < 4; ++r) {
      float m = sfr[0][r];
#pragma unroll
      for (int f = 1; f < 8; ++f) m = fmaxf(m, sfr[f][r]);
#pragma unroll
      for (int off = 1; off < 16; off <<= 1) m = fmaxf(m, __shfl_xor(m, off, 64));
      vm[r] = m;
    }
    if (ln == 0) {
#pragma unroll
      for (int r = 0; r < 4; ++r) stats[0][w][qd * 4 + r] = vm[r];
    }
  }
  __syncthreads();   // stats ready; all qp reads done -> safe to overwrite as P
  float gm[4];
#pragma unroll
  for (int r = 0; r < 4; ++r) {
    float m = stats[0][0][qd * 4 + r];
#pragma unroll
    for (int ww = 1; ww < 8; ++ww) m = fmaxf(m, stats[0][ww][qd * 4 + r]);
    gm[r] = m;
  }

  // ---- exp, row sum, write P (unnormalized) into qp alias
  float vs[4] = {0.f, 0.f, 0.f, 0.f};
#pragma unroll
  for (int f = 0; f < 8; ++f) {
    const int j = jbase + f * 16 + ln;
#pragma unroll
    for (int r = 0; r < 4; ++r) {
      float e = __expf(sfr[f][r] - gm[r]);
      vs[r] += e;
      qp[qd * 4 + r][j] = f2bf(e);
    }
  }
#pragma unroll
  for (int r = 0; r < 4; ++r) {
    float s = vs[r];
#pragma unroll
    for (int off = 1; off < 16; off <<= 1) s += __shfl_xor(s, off, 64);
    if (ln == 0) stats[1][w][qd * 4 + r] = s;
  }
  __syncthreads();   // P + sums ready
  float rrl[4];
#pragma unroll
  for (int r = 0; r < 4; ++r) {
    float s = 0.f;
#pragma unroll
    for (int ww = 0; ww < 8; ++ww) s += stats[1][ww][qd * 4 + r];
    rrl[r] = 1.0f / s;
  }

  // ---- phase 3: O = P @ v. Wave pair (w, w+4): dd-group g=w&3, k-half kh=w>>2.
  const int g = w & 3, kh = w >> 2;
  f32x4 oacc = {0.f, 0.f, 0.f, 0.f};
  {
    // stage 16 dd x 128 l = 256 uint4, 4/lane
    int vdd[4], vsg[4];
#pragma unroll
    for (int t = 0; t < 4; ++t) { int cid = t * 64 + lane; vdd[t] = cid >> 4; vsg[t] = (cid & 15) * 8; }
    const ushort* vb = vT + (size_t)(g * 16) * 1024 + kh * 512;
    uint4 pre[4];
#pragma unroll
    for (int t = 0; t < 4; ++t) pre[t] = *(const uint4*)(vb + (size_t)vdd[t] * 1024 + vsg[t]);
    for (int c = 0; c < 4; ++c) {
#pragma unroll
      for (int t = 0; t < 4; ++t) *(uint4*)(myst + vdd[t] * 136 + vsg[t]) = pre[t];
      if (c < 3) {
#pragma unroll
        for (int t = 0; t < 4; ++t)
          pre[t] = *(const uint4*)(vb + (size_t)vdd[t] * 1024 + (c + 1) * 128 + vsg[t]);
      }
#pragma unroll
      for (int kl = 0; kl < 4; ++kl) {
        const int kk = kh * 512 + c * 128 + kl * 32;
        bf16x8 ap = *(const bf16x8*)(&qp[ln][kk + qd * 8]);
        bf16x8 bv = *(const bf16x8*)(myst + ln * 136 + kl * 32 + qd * 8);
        oacc = __builtin_amdgcn_mfma_f32_16x16x32_bf16(ap, bv, oacc, 0, 0, 0);
      }
    }
  }

  // cross-half reduction through partner's retired staging region
  if (w >= 4) {
    float* red = (float*)myst;
#pragma unroll
    for (int cc = 0; cc < 4; ++cc) red[lane * 5 + cc] = oacc[cc];
  }
  __syncthreads();
  if (w < 4) {
    const float* red = (const float*)&stg[w + 4][0];
    const int b = bh >> 4, h = bh & 15;
    ushort* ob = Om + ((size_t)b * L_ * D_) + (size_t)h * DH + (size_t)(g * 16 + ln);
#pragma unroll
    for (int r = 0; r < 4; ++r) {
      float o = oacc[r] + red[lane * 5 + r];
      int row = i0 + qd * 4 + r;
      ob[(size_t)row * D_] = f2bf(o * rrl[r]);
    }
  }
}

extern "C" void kernel_launch(void* const* d_in, const int* in_sizes, int n_in,
                              void* d_out, int out_size, void* d_ws, size_t ws_size,
                              hipStream_t stream) {
  const float* query = (const float*)d_in[0];
  const float* key   = (const float*)d_in[1];
  const float* value = (const float*)d_in[2];
  const float* WQ    = (const float*)d_in[3];
  const float* WK    = (const float*)d_in[4];
  const float* WV    = (const float*)d_in[5];
  const float* Er    = (const float*)d_in[6];
  const float* WM    = (const float*)d_in[7];
  float* out = (float*)d_out;

  ushort* QW  = (ushort*)d_ws;
  ushort* KT  = QW  + (size_t)4096 * 1024;
  ushort* VT  = KT  + (size_t)4096 * 1024;
  ushort* O   = VT  + (size_t)4096 * 1024;
  ushort* Erb = O   + (size_t)4096 * 1024;
  ushort* WTQ = Erb + (size_t)65536;
  ushort* WTK = WTQ + (size_t)1024 * 1024;
  ushort* WTV = WTK + (size_t)1024 * 1024;
  ushort* WTM = WTV + (size_t)1024 * 1024;

  wT4_kernel<<<dim3(16, 16, 4), 256, 0, stream>>>(WQ, WK, WV, WM, WTQ, WTK, WTV, WTM);
  cvt_bf16_kernel<<<256, 256, 0, stream>>>(Er, Erb, L_ * DH);

  gemm_qkv_kernel<<<dim3(8, 32, 3), 256, 0, stream>>>(query, key, value,
                                                      WTQ, WTK, WTV,
                                                      QW, KT, VT);

  attn_kernel<<<dim3(64, 64), 512, 0, stream>>>(QW, KT, VT, Erb, O);

  gemm_mg_kernel<<<dim3(8, 32), 512, 0, stream>>>(O, WTM, out);
}

// Round 6
// 308.906 us; speedup vs baseline: 1.9844x; 1.1322x over previous
//
#include <hip/hip_runtime.h>

#define H_  16
#define L_  1024
#define D_  1024
#define DH  64

typedef short bf16x8 __attribute__((ext_vector_type(8)));
typedef float f32x4  __attribute__((ext_vector_type(4)));

__device__ __forceinline__ ushort f2bf(float f) {
  union { float f; unsigned int u; } x; x.f = f;
  unsigned int u = x.u;
  u = (u + 0x7fffu + ((u >> 16) & 1u)) >> 16;   // RNE
  return (ushort)u;
}
__device__ __forceinline__ float bf2f(ushort s) {
  union { unsigned int u; float f; } x; x.u = ((unsigned int)s) << 16;
  return x.f;
}

// Er fp32 [1024][64] -> ErF fragment-interleaved bf16.
// ErF slot t = ((jg*2+ph)*64 + lane)*8 + jj holds Er[jg*16 + (lane&15)][ph*32 + (lane>>4)*8 + jj].
__global__ __launch_bounds__(256) void erF_kernel(const float* __restrict__ Er,
                                                  ushort* __restrict__ ErF) {
  int t = blockIdx.x * 256 + threadIdx.x;   // [0, 8192)
  int lane = t & 63, ph = (t >> 6) & 1, jg = t >> 7;
  int m = jg * 16 + (lane & 15);
  int k = ph * 32 + (lane >> 4) * 8;
  float4 f0 = *(const float4*)(Er + m * 64 + k);
  float4 f1 = *(const float4*)(Er + m * 64 + k + 4);
  ushort4 u0, u1;
  u0.x = f2bf(f0.x); u0.y = f2bf(f0.y); u0.z = f2bf(f0.z); u0.w = f2bf(f0.w);
  u1.x = f2bf(f1.x); u1.y = f2bf(f1.y); u1.z = f2bf(f1.z); u1.w = f2bf(f1.w);
  *(ushort4*)(ErF + t * 8)     = u0;
  *(ushort4*)(ErF + t * 8 + 4) = u1;
}

// 4 weight transposes fused: W fp32 [1024][1024] -> WT bf16 [n][k]; z selects matrix.
__global__ __launch_bounds__(256) void wT4_kernel(
    const float* __restrict__ W0, const float* __restrict__ W1,
    const float* __restrict__ W2, const float* __restrict__ W3,
    ushort* __restrict__ T0, ushort* __restrict__ T1,
    ushort* __restrict__ T2, ushort* __restrict__ T3) {
  __shared__ ushort tt[64][72];
  const int z = blockIdx.z;
  const float* W = (z == 0) ? W0 : (z == 1) ? W1 : (z == 2) ? W2 : W3;
  ushort*     WT = (z == 0) ? T0 : (z == 1) ? T1 : (z == 2) ? T2 : T3;
  const int t = threadIdx.x;
  const int k0 = blockIdx.y * 64, n0 = blockIdx.x * 64;
#pragma unroll
  for (int c = 0; c < 4; ++c) {
    int k = c * 16 + (t >> 4);
    float4 f = *(const float4*)(W + (size_t)(k0 + k) * 1024 + n0 + (t & 15) * 4);
    tt[(t & 15) * 4 + 0][k] = f2bf(f.x);
    tt[(t & 15) * 4 + 1][k] = f2bf(f.y);
    tt[(t & 15) * 4 + 2][k] = f2bf(f.z);
    tt[(t & 15) * 4 + 3][k] = f2bf(f.w);
  }
  __syncthreads();
#pragma unroll
  for (int p = 0; p < 2; ++p) {
    int n = p * 32 + (t >> 3);
    *(uint4*)(WT + (size_t)(n0 + n) * 1024 + k0 + (t & 7) * 8) = *(const uint4*)(&tt[n][(t & 7) * 8]);
  }
}

// Fused Q/K/V projection GEMM: grid (8, 32, 3).
// z=0: QW bf16 row-major; z=1: KF fragment-interleaved; z=2: VF fragment-interleaved.
__global__ __launch_bounds__(256) void gemm_qkv_kernel(
    const float* __restrict__ Aq, const float* __restrict__ Ak, const float* __restrict__ Av,
    const ushort* __restrict__ BTq, const ushort* __restrict__ BTk, const ushort* __restrict__ BTv,
    ushort* __restrict__ Cq, ushort* __restrict__ Ck, ushort* __restrict__ Cv) {
  __shared__ ushort lsA[128][40];
  __shared__ ushort lsB[128][40];
  const int z = blockIdx.z;
  const float*  A  = (z == 0) ? Aq  : (z == 1) ? Ak  : Av;
  const ushort* BT = (z == 0) ? BTq : (z == 1) ? BTk : BTv;
  ushort*       Cp = (z == 0) ? Cq  : (z == 1) ? Ck  : Cv;

  const int tid  = threadIdx.x;
  const int w    = tid >> 6, lane = tid & 63, qd = lane >> 4, ln = lane & 15;
  const int rw   = w >> 1, cw = w & 1;
  const int m0   = blockIdx.y * 128, n0 = blockIdx.x * 128;

  f32x4 acc[16];
#pragma unroll
  for (int i = 0; i < 16; ++i) acc[i] = (f32x4){0.f, 0.f, 0.f, 0.f};

  for (int kb = 0; kb < 32; ++kb) {
    const int k0 = kb * 32;
    {
      int row = tid >> 1, half = tid & 1;
#pragma unroll
      for (int c = 0; c < 4; ++c) {
        float4 f = *(const float4*)(A + (size_t)(m0 + row) * 1024 + k0 + half * 16 + c * 4);
        ushort4 u;
        u.x = f2bf(f.x); u.y = f2bf(f.y); u.z = f2bf(f.z); u.w = f2bf(f.w);
        *(ushort4*)(&lsA[row][half * 16 + c * 4]) = u;
      }
    }
    {
      int row = tid >> 1, half = tid & 1;
#pragma unroll
      for (int c = 0; c < 2; ++c)
        *(uint4*)(&lsB[row][half * 16 + c * 8]) =
            *(const uint4*)(BT + (size_t)(n0 + row) * 1024 + k0 + half * 16 + c * 8);
    }
    __syncthreads();
    bf16x8 afr[4], bfr[4];
#pragma unroll
    for (int am = 0; am < 4; ++am)
      afr[am] = *(const bf16x8*)(&lsA[rw * 64 + am * 16 + ln][qd * 8]);
#pragma unroll
    for (int bn = 0; bn < 4; ++bn)
      bfr[bn] = *(const bf16x8*)(&lsB[cw * 64 + bn * 16 + ln][qd * 8]);
#pragma unroll
    for (int am = 0; am < 4; ++am)
#pragma unroll
      for (int bn = 0; bn < 4; ++bn)
        acc[am * 4 + bn] = __builtin_amdgcn_mfma_f32_16x16x32_bf16(afr[am], bfr[bn], acc[am * 4 + bn], 0, 0, 0);
    __syncthreads();
  }
#pragma unroll
  for (int am = 0; am < 4; ++am)
#pragma unroll
    for (int bn = 0; bn < 4; ++bn) {
      const int rbase = m0 + rw * 64 + am * 16 + qd * 4;
      const int colg  = n0 + cw * 64 + bn * 16 + ln;
      if (z == 0) {
#pragma unroll
        for (int r = 0; r < 4; ++r)
          Cp[(size_t)(rbase + r) * 1024 + colg] = f2bf(acc[am * 4 + bn][r]);
      } else if (z == 1) {
        // KF: rows are (bh, ki), col is j. Fragment slot:
        // ((jg*2+ph)*64 + lanep)*8 + jj, jg=j>>4, ph=ki>>5, lanep=((ki>>3)&3)*16+(j&15), jj=ki&7.
        const int bh  = rbase >> 6;
        const int ki0 = rbase & 63;         // +r consecutive, same 8-block
        const int jg  = colg >> 4;
        const int ph  = ki0 >> 5;
        const int lanep = ((ki0 >> 3) & 3) * 16 + (colg & 15);
        const int jj0 = ki0 & 7;
        ushort4 u;
        u.x = f2bf(acc[am * 4 + bn][0]); u.y = f2bf(acc[am * 4 + bn][1]);
        u.z = f2bf(acc[am * 4 + bn][2]); u.w = f2bf(acc[am * 4 + bn][3]);
        *(ushort4*)(Cp + (size_t)bh * 65536 + (size_t)((jg * 2 + ph) * 64 + lanep) * 8 + jj0) = u;
      } else {
        // VF: v[l][dd] with l=(row&63)*16+(colg>>6), dd=colg&63. Fragment slot:
        // ((g*32+ks)*64 + lanep)*8 + jj, g=dd>>4, ks=l>>5, lanep=((l>>3)&3)*16+(dd&15), jj=l&7.
        const int bh = rbase >> 6;
        const int llow = colg >> 6, dd = colg & 63;
        const int g = dd >> 4, lnf = dd & 15;
#pragma unroll
        for (int r = 0; r < 4; ++r) {
          int l = ((rbase + r) & 63) * 16 + llow;
          int ks = l >> 5;
          int lanep = ((l >> 3) & 3) * 16 + lnf;
          int jj = l & 7;
          Cp[(size_t)bh * 65536 + (size_t)((g * 32 + ks) * 64 + lanep) * 8 + jj] = f2bf(acc[am * 4 + bn][r]);
        }
      }
    }
}

// Merge GEMM with in-block split-K (unchanged).
__global__ __launch_bounds__(512) void gemm_mg_kernel(const ushort* __restrict__ A,
                                                      const ushort* __restrict__ BT,
                                                      float* __restrict__ Cp) {
  __shared__ ushort ls[2][2][128][40];
  const int tid  = threadIdx.x;
  const int w    = tid >> 6, lane = tid & 63, qd = lane >> 4, ln = lane & 15;
  const int kh   = w >> 2, q = w & 3;
  const int rw   = q >> 1, cw = q & 1;
  const int m0   = blockIdx.y * 128, n0 = blockIdx.x * 128;
  const int ts   = tid >> 8, tt = tid & 255;
  const int trow = tt >> 1, thalf = tt & 1;

  f32x4 acc[16];
#pragma unroll
  for (int i = 0; i < 16; ++i) acc[i] = (f32x4){0.f, 0.f, 0.f, 0.f};

  for (int kb = 0; kb < 16; ++kb) {
    const int k0 = ts * 512 + kb * 32;
#pragma unroll
    for (int c = 0; c < 2; ++c)
      *(uint4*)(&ls[ts][0][trow][thalf * 16 + c * 8]) =
          *(const uint4*)(A + (size_t)(m0 + trow) * 1024 + k0 + thalf * 16 + c * 8);
#pragma unroll
    for (int c = 0; c < 2; ++c)
      *(uint4*)(&ls[ts][1][trow][thalf * 16 + c * 8]) =
          *(const uint4*)(BT + (size_t)(n0 + trow) * 1024 + k0 + thalf * 16 + c * 8);
    __syncthreads();
    bf16x8 afr[4], bfr[4];
#pragma unroll
    for (int am = 0; am < 4; ++am)
      afr[am] = *(const bf16x8*)(&ls[kh][0][rw * 64 + am * 16 + ln][qd * 8]);
#pragma unroll
    for (int bn = 0; bn < 4; ++bn)
      bfr[bn] = *(const bf16x8*)(&ls[kh][1][cw * 64 + bn * 16 + ln][qd * 8]);
#pragma unroll
    for (int am = 0; am < 4; ++am)
#pragma unroll
      for (int bn = 0; bn < 4; ++bn)
        acc[am * 4 + bn] = __builtin_amdgcn_mfma_f32_16x16x32_bf16(afr[am], bfr[bn], acc[am * 4 + bn], 0, 0, 0);
    __syncthreads();
  }

  float* red = (float*)&ls[0][0][0][0];
  for (int half = 0; half < 2; ++half) {
    __syncthreads();
    if (w >= 4) {
      const int base = ((w - 4) * 64 + lane) * 33;
#pragma unroll
      for (int i = 0; i < 8; ++i)
#pragma unroll
        for (int c = 0; c < 4; ++c) red[base + i * 4 + c] = acc[half * 8 + i][c];
    }
    __syncthreads();
    if (w < 4) {
      const int base = (w * 64 + lane) * 33;
#pragma unroll
      for (int i = 0; i < 8; ++i)
#pragma unroll
        for (int c = 0; c < 4; ++c) acc[half * 8 + i][c] += red[base + i * 4 + c];
    }
  }
  if (w < 4) {
#pragma unroll
    for (int am = 0; am < 4; ++am)
#pragma unroll
      for (int bn = 0; bn < 4; ++bn) {
        const int rbase = m0 + rw * 64 + am * 16 + qd * 4;
        const int colg  = n0 + cw * 64 + bn * 16 + ln;
#pragma unroll
        for (int r = 0; r < 4; ++r)
          Cp[(size_t)(rbase + r) * 1024 + colg] = acc[am * 4 + bn][r];
      }
  }
}

// Fused relative attention, 512 threads / 8 waves, fragment-direct B operands.
// Block = (bh, 16 Q-rows). Wave w owns cols [w*128, w*128+128); PV split-K across wave pairs.
// KF/VF/ErF are fragment-interleaved: one global_load_dwordx4 at base+lane*16 = one B-fragment.
__global__ __launch_bounds__(512, 4) void attn_kernel(
    const ushort* __restrict__ QW, const ushort* __restrict__ KF,
    const ushort* __restrict__ VF, const ushort* __restrict__ ErF,
    ushort* __restrict__ Om) {
  __shared__ ushort qp[17][1032];    // QEr rows i0..i0+16; later aliased as P[16][1024]
  __shared__ float  red[4][64][4];   // PV cross-half reduction
  __shared__ float  stats[2][8][16];

  const int tid  = threadIdx.x;
  const int w    = tid >> 6;
  const int lane = tid & 63;
  const int qd   = lane >> 4;
  const int ln   = lane & 15;
  const int bh   = blockIdx.y;
  const int i0   = blockIdx.x << 4;
  const ushort* q  = QW + ((size_t)bh << 16);
  const ushort* kf = KF + ((size_t)bh << 16);
  const ushort* vf = VF + ((size_t)bh << 16);

  // A-fragments straight from global (q rows i0..i0+15 and broadcast row i0+16)
  bf16x8 a00 = *(const bf16x8*)(q + (size_t)(i0 + ln) * 64 + qd * 8);
  bf16x8 a01 = *(const bf16x8*)(q + (size_t)(i0 + ln) * 64 + 32 + qd * 8);
  const int row16 = (i0 + 16 > 1023) ? 1023 : i0 + 16;
  bf16x8 a10 = *(const bf16x8*)(q + (size_t)row16 * 64 + qd * 8);
  bf16x8 a11 = *(const bf16x8*)(q + (size_t)row16 * 64 + 32 + qd * 8);

  const int jg0 = w * 8;   // wave's 8 column-groups of 16

  // ---- phase 0: QEr cols [w*128, w*128+128) -> qp rows 0..16
#pragma unroll
  for (int f = 0; f < 8; ++f) {
    const int jg = jg0 + f;
    bf16x8 b0 = *(const bf16x8*)(ErF + (size_t)((jg * 2 + 0) * 64 + lane) * 8);
    bf16x8 b1 = *(const bf16x8*)(ErF + (size_t)((jg * 2 + 1) * 64 + lane) * 8);
    f32x4 acc = {0.f, 0.f, 0.f, 0.f};
    acc = __builtin_amdgcn_mfma_f32_16x16x32_bf16(a00, b0, acc, 0, 0, 0);
    acc = __builtin_amdgcn_mfma_f32_16x16x32_bf16(a01, b1, acc, 0, 0, 0);
    const int m = jg * 16 + ln;
#pragma unroll
    for (int r = 0; r < 4; ++r) qp[qd * 4 + r][m] = f2bf(acc[r]);
    if (jg * 16 <= 1006 - i0) {   // row i0+16: only prefix columns ever read
      f32x4 ac2 = {0.f, 0.f, 0.f, 0.f};
      ac2 = __builtin_amdgcn_mfma_f32_16x16x32_bf16(a10, b0, ac2, 0, 0, 0);
      ac2 = __builtin_amdgcn_mfma_f32_16x16x32_bf16(a11, b1, ac2, 0, 0, 0);
      if (qd == 0) qp[16][m] = f2bf(ac2[0]);
    }
  }

  // ---- phase 1: S = q @ kT, fragment-direct KF loads (independent of qp)
  f32x4 sfr[8];
#pragma unroll
  for (int f = 0; f < 8; ++f) {
    const int jg = jg0 + f;
    bf16x8 b0 = *(const bf16x8*)(kf + (size_t)((jg * 2 + 0) * 64 + lane) * 8);
    bf16x8 b1 = *(const bf16x8*)(kf + (size_t)((jg * 2 + 1) * 64 + lane) * 8);
    f32x4 acc = {0.f, 0.f, 0.f, 0.f};
    acc = __builtin_amdgcn_mfma_f32_16x16x32_bf16(a00, b0, acc, 0, 0, 0);
    acc = __builtin_amdgcn_mfma_f32_16x16x32_bf16(a01, b1, acc, 0, 0, 0);
    sfr[f] = acc;
  }
  __syncthreads();   // qp (QEr) complete across all waves

  // ---- skew-add Srel + scale 1/sqrt(64)
#pragma unroll
  for (int f = 0; f < 8; ++f) {
    const int j = w * 128 + f * 16 + ln;
#pragma unroll
    for (int r = 0; r < 4; ++r) {
      int rloc = qd * 4 + r;
      int i = i0 + rloc;
      float srel;
      if (j <= i)          srel = bf2f(qp[rloc][1023 - i + j]);
      else if (j == i + 1) srel = 0.f;
      else                 srel = bf2f(qp[rloc + 1][j - i - 2]);
      sfr[f][r] = (sfr[f][r] + srel) * 0.125f;
    }
  }

  // ---- row max
  {
    float vm[4];
#pragma unroll
    for (int r = 0; r < 4; ++r) {
      float m = sfr[0][r];
#pragma unroll
      for (int f = 1; f < 8; ++f) m = fmaxf(m, sfr[f][r]);
#pragma unroll
      for (int off = 1; off < 16; off <<= 1) m = fmaxf(m, __shfl_xor(m, off, 64));
      vm[r] = m;
    }
    if (ln == 0) {
#pragma unroll
      for (int r = 0; r < 4; ++r) stats[0][w][qd * 4 + r] = vm[r];
    }
  }
  __syncthreads();   // stats ready; all qp(QEr) reads done -> safe to overwrite as P
  float gm[4];
#pragma unroll
  for (int r = 0; r < 4; ++r) {
    float m = stats[0][0][qd * 4 + r];
#pragma unroll
    for (int ww = 1; ww < 8; ++ww) m = fmaxf(m, stats[0][ww][qd * 4 + r]);
    gm[r] = m;
  }

  // ---- exp, row sum, write P (unnormalized) into qp alias
  float vs[4] = {0.f, 0.f, 0.f, 0.f};
#pragma unroll
  for (int f = 0; f < 8; ++f) {
    const int j = w * 128 + f * 16 + ln;
#pragma unroll
    for (int r = 0; r < 4; ++r) {
      float e = __expf(sfr[f][r] - gm[r]);
      vs[r] += e;
      qp[qd * 4 + r][j] = f2bf(e);
    }
  }
#pragma unroll
  for (int r = 0; r < 4; ++r) {
    float s = vs[r];
#pragma unroll
    for (int off = 1; off < 16; off <<= 1) s += __shfl_xor(s, off, 64);
    if (ln == 0) stats[1][w][qd * 4 + r] = s;
  }
  __syncthreads();   // P + sums ready
  float rrl[4];
#pragma unroll
  for (int r = 0; r < 4; ++r) {
    float s = 0.f;
#pragma unroll
    for (int ww = 0; ww < 8; ++ww) s += stats[1][ww][qd * 4 + r];
    rrl[r] = 1.0f / s;
  }

  // ---- phase 3: O = P @ v. Wave pair (g = w&3 owns dd-group, kh = w>>2 owns K-half).
  const int g = w & 3, kh = w >> 2;
  f32x4 oacc = {0.f, 0.f, 0.f, 0.f};
#pragma unroll
  for (int kc = 0; kc < 16; ++kc) {
    const int ks = kh * 16 + kc;
    bf16x8 ap = *(const bf16x8*)(&qp[ln][ks * 32 + qd * 8]);
    bf16x8 bv = *(const bf16x8*)(vf + (size_t)((g * 32 + ks) * 64 + lane) * 8);
    oacc = __builtin_amdgcn_mfma_f32_16x16x32_bf16(ap, bv, oacc, 0, 0, 0);
  }

  // cross-half reduction
  if (w >= 4) {
#pragma unroll
    for (int cc = 0; cc < 4; ++cc) red[w - 4][lane][cc] = oacc[cc];
  }
  __syncthreads();
  if (w < 4) {
    const int b = bh >> 4, h = bh & 15;
    ushort* ob = Om + ((size_t)b * L_ * D_) + (size_t)h * DH + (size_t)(g * 16 + ln);
#pragma unroll
    for (int r = 0; r < 4; ++r) {
      float o = oacc[r] + red[w][lane][r];
      int row = i0 + qd * 4 + r;
      ob[(size_t)row * D_] = f2bf(o * rrl[r]);
    }
  }
}

extern "C" void kernel_launch(void* const* d_in, const int* in_sizes, int n_in,
                              void* d_out, int out_size, void* d_ws, size_t ws_size,
                              hipStream_t stream) {
  const float* query = (const float*)d_in[0];
  const float* key   = (const float*)d_in[1];
  const float* value = (const float*)d_in[2];
  const float* WQ    = (const float*)d_in[3];
  const float* WK    = (const float*)d_in[4];
  const float* WV    = (const float*)d_in[5];
  const float* Er    = (const float*)d_in[6];
  const float* WM    = (const float*)d_in[7];
  float* out = (float*)d_out;

  ushort* QW  = (ushort*)d_ws;
  ushort* KF  = QW  + (size_t)4096 * 1024;
  ushort* VF  = KF  + (size_t)4096 * 1024;
  ushort* O   = VF  + (size_t)4096 * 1024;
  ushort* ErF = O   + (size_t)4096 * 1024;
  ushort* WTQ = ErF + (size_t)65536;
  ushort* WTK = WTQ + (size_t)1024 * 1024;
  ushort* WTV = WTK + (size_t)1024 * 1024;
  ushort* WTM = WTV + (size_t)1024 * 1024;

  wT4_kernel<<<dim3(16, 16, 4), 256, 0, stream>>>(WQ, WK, WV, WM, WTQ, WTK, WTV, WTM);
  erF_kernel<<<32, 256, 0, stream>>>(Er, ErF);

  gemm_qkv_kernel<<<dim3(8, 32, 3), 256, 0, stream>>>(query, key, value,
                                                      WTQ, WTK, WTV,
                                                      QW, KF, VF);

  attn_kernel<<<dim3(64, 64), 512, 0, stream>>>(QW, KF, VF, ErF, O);

  gemm_mg_kernel<<<dim3(8, 32), 512, 0, stream>>>(O, WTM, out);
}

// Round 7
// 297.973 us; speedup vs baseline: 2.0572x; 1.0367x over previous
//
#include <hip/hip_runtime.h>

#define H_  16
#define L_  1024
#define D_  1024
#define DH  64

typedef short bf16x8 __attribute__((ext_vector_type(8)));
typedef float f32x4  __attribute__((ext_vector_type(4)));

__device__ __forceinline__ ushort f2bf(float f) {
  union { float f; unsigned int u; } x; x.f = f;
  unsigned int u = x.u;
  u = (u + 0x7fffu + ((u >> 16) & 1u)) >> 16;   // RNE
  return (ushort)u;
}
__device__ __forceinline__ float bf2f(ushort s) {
  union { unsigned int u; float f; } x; x.u = ((unsigned int)s) << 16;
  return x.f;
}

// q/k/v fp32 -> bf16, memory-bound. 8 floats per thread.
__global__ __launch_bounds__(256) void cvt3_kernel(
    const float* __restrict__ q, const float* __restrict__ k, const float* __restrict__ v,
    ushort* __restrict__ qb, ushort* __restrict__ kb, ushort* __restrict__ vb) {
  const int z = blockIdx.y;
  const float* in = (z == 0) ? q : (z == 1) ? k : v;
  ushort* out = (z == 0) ? qb : (z == 1) ? kb : vb;
  int i = (blockIdx.x * 256 + threadIdx.x) * 8;
  float4 f0 = *(const float4*)(in + i);
  float4 f1 = *(const float4*)(in + i + 4);
  ushort u[8] = {f2bf(f0.x), f2bf(f0.y), f2bf(f0.z), f2bf(f0.w),
                 f2bf(f1.x), f2bf(f1.y), f2bf(f1.z), f2bf(f1.w)};
  *(uint4*)(out + i) = *(uint4*)u;
}

// Er fp32 [1024][64] -> ErF fragment-interleaved bf16.
__global__ __launch_bounds__(256) void erF_kernel(const float* __restrict__ Er,
                                                  ushort* __restrict__ ErF) {
  int t = blockIdx.x * 256 + threadIdx.x;   // [0, 8192)
  int lane = t & 63, ph = (t >> 6) & 1, jg = t >> 7;
  int m = jg * 16 + (lane & 15);
  int k = ph * 32 + (lane >> 4) * 8;
  float4 f0 = *(const float4*)(Er + m * 64 + k);
  float4 f1 = *(const float4*)(Er + m * 64 + k + 4);
  ushort4 u0, u1;
  u0.x = f2bf(f0.x); u0.y = f2bf(f0.y); u0.z = f2bf(f0.z); u0.w = f2bf(f0.w);
  u1.x = f2bf(f1.x); u1.y = f2bf(f1.y); u1.z = f2bf(f1.z); u1.w = f2bf(f1.w);
  *(ushort4*)(ErF + t * 8)     = u0;
  *(ushort4*)(ErF + t * 8 + 4) = u1;
}

// 4 weight transposes fused: W fp32 [1024][1024] -> WT bf16 [n][k].
__global__ __launch_bounds__(256) void wT4_kernel(
    const float* __restrict__ W0, const float* __restrict__ W1,
    const float* __restrict__ W2, const float* __restrict__ W3,
    ushort* __restrict__ T0, ushort* __restrict__ T1,
    ushort* __restrict__ T2, ushort* __restrict__ T3) {
  __shared__ ushort tt[64][72];
  const int z = blockIdx.z;
  const float* W = (z == 0) ? W0 : (z == 1) ? W1 : (z == 2) ? W2 : W3;
  ushort*     WT = (z == 0) ? T0 : (z == 1) ? T1 : (z == 2) ? T2 : T3;
  const int t = threadIdx.x;
  const int k0 = blockIdx.y * 64, n0 = blockIdx.x * 64;
#pragma unroll
  for (int c = 0; c < 4; ++c) {
    int k = c * 16 + (t >> 4);
    float4 f = *(const float4*)(W + (size_t)(k0 + k) * 1024 + n0 + (t & 15) * 4);
    tt[(t & 15) * 4 + 0][k] = f2bf(f.x);
    tt[(t & 15) * 4 + 1][k] = f2bf(f.y);
    tt[(t & 15) * 4 + 2][k] = f2bf(f.z);
    tt[(t & 15) * 4 + 3][k] = f2bf(f.w);
  }
  __syncthreads();
#pragma unroll
  for (int p = 0; p < 2; ++p) {
    int n = p * 32 + (t >> 3);
    *(uint4*)(WT + (size_t)(n0 + n) * 1024 + k0 + (t & 7) * 8) = *(const uint4*)(&tt[n][(t & 7) * 8]);
  }
}

// Fused Q/K/V projection GEMM: grid (8, 32, 3). A is pre-converted bf16.
// z=0: QW bf16 row-major; z=1: KF fragment-interleaved; z=2: VF fragment-interleaved.
__global__ __launch_bounds__(256) void gemm_qkv_kernel(
    const ushort* __restrict__ Aq, const ushort* __restrict__ Ak, const ushort* __restrict__ Av,
    const ushort* __restrict__ BTq, const ushort* __restrict__ BTk, const ushort* __restrict__ BTv,
    ushort* __restrict__ Cq, ushort* __restrict__ Ck, ushort* __restrict__ Cv) {
  __shared__ ushort lsA[128][40];
  __shared__ ushort lsB[128][40];
  const int z = blockIdx.z;
  const ushort* A  = (z == 0) ? Aq  : (z == 1) ? Ak  : Av;
  const ushort* BT = (z == 0) ? BTq : (z == 1) ? BTk : BTv;
  ushort*       Cp = (z == 0) ? Cq  : (z == 1) ? Ck  : Cv;

  const int tid  = threadIdx.x;
  const int w    = tid >> 6, lane = tid & 63, qd = lane >> 4, ln = lane & 15;
  const int rw   = w >> 1, cw = w & 1;
  const int m0   = blockIdx.y * 128, n0 = blockIdx.x * 128;

  f32x4 acc[16];
#pragma unroll
  for (int i = 0; i < 16; ++i) acc[i] = (f32x4){0.f, 0.f, 0.f, 0.f};

  for (int kb = 0; kb < 32; ++kb) {
    const int k0 = kb * 32;
    const int row = tid >> 1, half = tid & 1;
#pragma unroll
    for (int c = 0; c < 2; ++c)
      *(uint4*)(&lsA[row][half * 16 + c * 8]) =
          *(const uint4*)(A + (size_t)(m0 + row) * 1024 + k0 + half * 16 + c * 8);
#pragma unroll
    for (int c = 0; c < 2; ++c)
      *(uint4*)(&lsB[row][half * 16 + c * 8]) =
          *(const uint4*)(BT + (size_t)(n0 + row) * 1024 + k0 + half * 16 + c * 8);
    __syncthreads();
    bf16x8 afr[4], bfr[4];
#pragma unroll
    for (int am = 0; am < 4; ++am)
      afr[am] = *(const bf16x8*)(&lsA[rw * 64 + am * 16 + ln][qd * 8]);
#pragma unroll
    for (int bn = 0; bn < 4; ++bn)
      bfr[bn] = *(const bf16x8*)(&lsB[cw * 64 + bn * 16 + ln][qd * 8]);
#pragma unroll
    for (int am = 0; am < 4; ++am)
#pragma unroll
      for (int bn = 0; bn < 4; ++bn)
        acc[am * 4 + bn] = __builtin_amdgcn_mfma_f32_16x16x32_bf16(afr[am], bfr[bn], acc[am * 4 + bn], 0, 0, 0);
    __syncthreads();
  }
#pragma unroll
  for (int am = 0; am < 4; ++am)
#pragma unroll
    for (int bn = 0; bn < 4; ++bn) {
      const int rbase = m0 + rw * 64 + am * 16 + qd * 4;
      const int colg  = n0 + cw * 64 + bn * 16 + ln;
      if (z == 0) {
#pragma unroll
        for (int r = 0; r < 4; ++r)
          Cp[(size_t)(rbase + r) * 1024 + colg] = f2bf(acc[am * 4 + bn][r]);
      } else if (z == 1) {
        const int bh  = rbase >> 6;
        const int ki0 = rbase & 63;
        const int jg  = colg >> 4;
        const int ph  = ki0 >> 5;
        const int lanep = ((ki0 >> 3) & 3) * 16 + (colg & 15);
        const int jj0 = ki0 & 7;
        ushort4 u;
        u.x = f2bf(acc[am * 4 + bn][0]); u.y = f2bf(acc[am * 4 + bn][1]);
        u.z = f2bf(acc[am * 4 + bn][2]); u.w = f2bf(acc[am * 4 + bn][3]);
        *(ushort4*)(Cp + (size_t)bh * 65536 + (size_t)((jg * 2 + ph) * 64 + lanep) * 8 + jj0) = u;
      } else {
        const int bh = rbase >> 6;
        const int llow = colg >> 6, dd = colg & 63;
        const int g = dd >> 4, lnf = dd & 15;
#pragma unroll
        for (int r = 0; r < 4; ++r) {
          int l = ((rbase + r) & 63) * 16 + llow;
          int ks = l >> 5;
          int lanep = ((l >> 3) & 3) * 16 + lnf;
          int jj = l & 7;
          Cp[(size_t)bh * 65536 + (size_t)((g * 32 + ks) * 64 + lanep) * 8 + jj] = f2bf(acc[am * 4 + bn][r]);
        }
      }
    }
}

// Merge GEMM with in-block split-K (unchanged).
__global__ __launch_bounds__(512) void gemm_mg_kernel(const ushort* __restrict__ A,
                                                      const ushort* __restrict__ BT,
                                                      float* __restrict__ Cp) {
  __shared__ ushort ls[2][2][128][40];
  const int tid  = threadIdx.x;
  const int w    = tid >> 6, lane = tid & 63, qd = lane >> 4, ln = lane & 15;
  const int kh   = w >> 2, q = w & 3;
  const int rw   = q >> 1, cw = q & 1;
  const int m0   = blockIdx.y * 128, n0 = blockIdx.x * 128;
  const int ts   = tid >> 8, tt = tid & 255;
  const int trow = tt >> 1, thalf = tt & 1;

  f32x4 acc[16];
#pragma unroll
  for (int i = 0; i < 16; ++i) acc[i] = (f32x4){0.f, 0.f, 0.f, 0.f};

  for (int kb = 0; kb < 16; ++kb) {
    const int k0 = ts * 512 + kb * 32;
#pragma unroll
    for (int c = 0; c < 2; ++c)
      *(uint4*)(&ls[ts][0][trow][thalf * 16 + c * 8]) =
          *(const uint4*)(A + (size_t)(m0 + trow) * 1024 + k0 + thalf * 16 + c * 8);
#pragma unroll
    for (int c = 0; c < 2; ++c)
      *(uint4*)(&ls[ts][1][trow][thalf * 16 + c * 8]) =
          *(const uint4*)(BT + (size_t)(n0 + trow) * 1024 + k0 + thalf * 16 + c * 8);
    __syncthreads();
    bf16x8 afr[4], bfr[4];
#pragma unroll
    for (int am = 0; am < 4; ++am)
      afr[am] = *(const bf16x8*)(&ls[kh][0][rw * 64 + am * 16 + ln][qd * 8]);
#pragma unroll
    for (int bn = 0; bn < 4; ++bn)
      bfr[bn] = *(const bf16x8*)(&ls[kh][1][cw * 64 + bn * 16 + ln][qd * 8]);
#pragma unroll
    for (int am = 0; am < 4; ++am)
#pragma unroll
      for (int bn = 0; bn < 4; ++bn)
        acc[am * 4 + bn] = __builtin_amdgcn_mfma_f32_16x16x32_bf16(afr[am], bfr[bn], acc[am * 4 + bn], 0, 0, 0);
    __syncthreads();
  }

  float* red = (float*)&ls[0][0][0][0];
  for (int half = 0; half < 2; ++half) {
    __syncthreads();
    if (w >= 4) {
      const int base = ((w - 4) * 64 + lane) * 33;
#pragma unroll
      for (int i = 0; i < 8; ++i)
#pragma unroll
        for (int c = 0; c < 4; ++c) red[base + i * 4 + c] = acc[half * 8 + i][c];
    }
    __syncthreads();
    if (w < 4) {
      const int base = (w * 64 + lane) * 33;
#pragma unroll
      for (int i = 0; i < 8; ++i)
#pragma unroll
        for (int c = 0; c < 4; ++c) acc[half * 8 + i][c] += red[base + i * 4 + c];
    }
  }
  if (w < 4) {
#pragma unroll
    for (int am = 0; am < 4; ++am)
#pragma unroll
      for (int bn = 0; bn < 4; ++bn) {
        const int rbase = m0 + rw * 64 + am * 16 + qd * 4;
        const int colg  = n0 + cw * 64 + bn * 16 + ln;
#pragma unroll
        for (int r = 0; r < 4; ++r)
          Cp[(size_t)(rbase + r) * 1024 + colg] = acc[am * 4 + bn][r];
      }
  }
}

// Fused relative attention, 512 threads / 8 waves, fragment-direct B operands.
// QEr lives in a flat stride-1025 LDS region: Srel[i][j] = qflat[rloc*1024 + 1023-i0+j]
// (pad slot between rows = the j==i+1 zero). P aliases the region at stride 1048.
__global__ __launch_bounds__(512, 4) void attn_kernel(
    const ushort* __restrict__ QW, const ushort* __restrict__ KF,
    const ushort* __restrict__ VF, const ushort* __restrict__ ErF,
    ushort* __restrict__ Om) {
  __shared__ ushort qflat[17440];    // QEr rows 0..16 @ r*1025; P rows 0..15 @ r*1048
  __shared__ float  red[4][64][4];
  __shared__ float  stats[2][8][16];

  const int tid  = threadIdx.x;
  const int w    = tid >> 6;
  const int lane = tid & 63;
  const int qd   = lane >> 4;
  const int ln   = lane & 15;
  const int bh   = blockIdx.y;
  const int i0   = blockIdx.x << 4;
  const ushort* q  = QW + ((size_t)bh << 16);
  const ushort* kf = KF + ((size_t)bh << 16);
  const ushort* vf = VF + ((size_t)bh << 16);

  if (tid < 16) qflat[tid * 1025 + 1024] = 0;   // the j==i+1 zeros

  // A-fragments straight from global
  bf16x8 a00 = *(const bf16x8*)(q + (size_t)(i0 + ln) * 64 + qd * 8);
  bf16x8 a01 = *(const bf16x8*)(q + (size_t)(i0 + ln) * 64 + 32 + qd * 8);
  const int row16 = (i0 + 16 > 1023) ? 1023 : i0 + 16;
  bf16x8 a10 = *(const bf16x8*)(q + (size_t)row16 * 64 + qd * 8);
  bf16x8 a11 = *(const bf16x8*)(q + (size_t)row16 * 64 + 32 + qd * 8);

  const int jg0 = w * 8;

  // ---- phase 0: QEr cols [w*128, w*128+128) -> qflat rows 0..16 (stride 1025)
#pragma unroll
  for (int f = 0; f < 8; ++f) {
    const int jg = jg0 + f;
    bf16x8 b0 = *(const bf16x8*)(ErF + (size_t)((jg * 2 + 0) * 64 + lane) * 8);
    bf16x8 b1 = *(const bf16x8*)(ErF + (size_t)((jg * 2 + 1) * 64 + lane) * 8);
    f32x4 acc = {0.f, 0.f, 0.f, 0.f};
    acc = __builtin_amdgcn_mfma_f32_16x16x32_bf16(a00, b0, acc, 0, 0, 0);
    acc = __builtin_amdgcn_mfma_f32_16x16x32_bf16(a01, b1, acc, 0, 0, 0);
    const int m = jg * 16 + ln;
#pragma unroll
    for (int r = 0; r < 4; ++r) qflat[(qd * 4 + r) * 1025 + m] = f2bf(acc[r]);
    if (jg * 16 <= 1006 - i0) {   // row i0+16 prefix
      f32x4 ac2 = {0.f, 0.f, 0.f, 0.f};
      ac2 = __builtin_amdgcn_mfma_f32_16x16x32_bf16(a10, b0, ac2, 0, 0, 0);
      ac2 = __builtin_amdgcn_mfma_f32_16x16x32_bf16(a11, b1, ac2, 0, 0, 0);
      if (qd == 0) qflat[16 * 1025 + m] = f2bf(ac2[0]);
    }
  }

  // ---- phase 1: S = q @ kT (independent of qflat)
  f32x4 sfr[8];
#pragma unroll
  for (int f = 0; f < 8; ++f) {
    const int jg = jg0 + f;
    bf16x8 b0 = *(const bf16x8*)(kf + (size_t)((jg * 2 + 0) * 64 + lane) * 8);
    bf16x8 b1 = *(const bf16x8*)(kf + (size_t)((jg * 2 + 1) * 64 + lane) * 8);
    f32x4 acc = {0.f, 0.f, 0.f, 0.f};
    acc = __builtin_amdgcn_mfma_f32_16x16x32_bf16(a00, b0, acc, 0, 0, 0);
    acc = __builtin_amdgcn_mfma_f32_16x16x32_bf16(a01, b1, acc, 0, 0, 0);
    sfr[f] = acc;
  }
  __syncthreads();   // QEr complete across all waves

  // ---- skew-add Srel: branch-free flat gather (scale deferred to exp2)
#pragma unroll
  for (int f = 0; f < 8; ++f) {
    const int cj = 1023 - i0 + w * 128 + f * 16 + ln;
#pragma unroll
    for (int r = 0; r < 4; ++r)
      sfr[f][r] += bf2f(qflat[(qd * 4 + r) * 1024 + cj]);
  }

  // ---- row max (of unscaled sums; max commutes with the positive scale)
  {
    float vm[4];
#pragma unroll
    for (int r = 0; r < 4; ++r) {
      float m = sfr[0][r];
#pragma unroll
      for (int f = 1; f < 8; ++f) m = fmaxf(m, sfr[f][r]);
#pragma unroll
      for (int off = 1; off < 16; off <<= 1) m = fmaxf(m, __shfl_xor(m, off, 64));
      vm[r] = m;
    }
    if (ln == 0) {
#pragma unroll
      for (int r = 0; r < 4; ++r) stats[0][w][qd * 4 + r] = vm[r];
    }
  }
  __syncthreads();   // stats ready; all QEr reads done -> safe to overwrite as P
  const float cexp = 0.18033688011112042f;   // 0.125 * log2(e)
  float gm2[4];
#pragma unroll
  for (int r = 0; r < 4; ++r) {
    float m = stats[0][0][qd * 4 + r];
#pragma unroll
    for (int ww = 1; ww < 8; ++ww) m = fmaxf(m, stats[0][ww][qd * 4 + r]);
    gm2[r] = -m * cexp;
  }

  // ---- exp2, row sum, write P (unnormalized) at stride 1048
  float vs[4] = {0.f, 0.f, 0.f, 0.f};
#pragma unroll
  for (int f = 0; f < 8; ++f) {
    const int j = w * 128 + f * 16 + ln;
#pragma unroll
    for (int r = 0; r < 4; ++r) {
      float e = exp2f(fmaf(sfr[f][r], cexp, gm2[r]));
      vs[r] += e;
      qflat[(qd * 4 + r) * 1048 + j] = f2bf(e);
    }
  }
#pragma unroll
  for (int r = 0; r < 4; ++r) {
    float s = vs[r];
#pragma unroll
    for (int off = 1; off < 16; off <<= 1) s += __shfl_xor(s, off, 64);
    if (ln == 0) stats[1][w][qd * 4 + r] = s;
  }
  __syncthreads();   // P + sums ready
  float rrl[4];
#pragma unroll
  for (int r = 0; r < 4; ++r) {
    float s = 0.f;
#pragma unroll
    for (int ww = 0; ww < 8; ++ww) s += stats[1][ww][qd * 4 + r];
    rrl[r] = 1.0f / s;
  }

  // ---- phase 3: O = P @ v (split-K across wave pairs)
  const int g = w & 3, kh = w >> 2;
  f32x4 oacc = {0.f, 0.f, 0.f, 0.f};
#pragma unroll
  for (int kc = 0; kc < 16; ++kc) {
    const int ks = kh * 16 + kc;
    bf16x8 ap = *(const bf16x8*)(qflat + ln * 1048 + ks * 32 + qd * 8);
    bf16x8 bv = *(const bf16x8*)(vf + (size_t)((g * 32 + ks) * 64 + lane) * 8);
    oacc = __builtin_amdgcn_mfma_f32_16x16x32_bf16(ap, bv, oacc, 0, 0, 0);
  }

  if (w >= 4) {
#pragma unroll
    for (int cc = 0; cc < 4; ++cc) red[w - 4][lane][cc] = oacc[cc];
  }
  __syncthreads();
  if (w < 4) {
    const int b = bh >> 4, h = bh & 15;
    ushort* ob = Om + ((size_t)b * L_ * D_) + (size_t)h * DH + (size_t)(g * 16 + ln);
#pragma unroll
    for (int r = 0; r < 4; ++r) {
      float o = oacc[r] + red[w][lane][r];
      int row = i0 + qd * 4 + r;
      ob[(size_t)row * D_] = f2bf(o * rrl[r]);
    }
  }
}

extern "C" void kernel_launch(void* const* d_in, const int* in_sizes, int n_in,
                              void* d_out, int out_size, void* d_ws, size_t ws_size,
                              hipStream_t stream) {
  const float* query = (const float*)d_in[0];
  const float* key   = (const float*)d_in[1];
  const float* value = (const float*)d_in[2];
  const float* WQ    = (const float*)d_in[3];
  const float* WK    = (const float*)d_in[4];
  const float* WV    = (const float*)d_in[5];
  const float* Er    = (const float*)d_in[6];
  const float* WM    = (const float*)d_in[7];
  float* out = (float*)d_out;

  // workspace (ushort units): QW,KF,VF,O 4M each; ErF 64K; 4 WT 1M each; KB,VB 4M each.
  // QB (bf16 query) aliases O: O is written only by attn, after the qkv GEMM consumed QB.
  ushort* QW  = (ushort*)d_ws;
  ushort* KF  = QW  + (size_t)4096 * 1024;
  ushort* VF  = KF  + (size_t)4096 * 1024;
  ushort* O   = VF  + (size_t)4096 * 1024;
  ushort* ErF = O   + (size_t)4096 * 1024;
  ushort* WTQ = ErF + (size_t)65536;
  ushort* WTK = WTQ + (size_t)1024 * 1024;
  ushort* WTV = WTK + (size_t)1024 * 1024;
  ushort* WTM = WTV + (size_t)1024 * 1024;
  ushort* KB  = WTM + (size_t)1024 * 1024;
  ushort* VB  = KB  + (size_t)4096 * 1024;
  ushort* QB  = O;   // alias

  cvt3_kernel<<<dim3(2048, 3), 256, 0, stream>>>(query, key, value, QB, KB, VB);
  wT4_kernel<<<dim3(16, 16, 4), 256, 0, stream>>>(WQ, WK, WV, WM, WTQ, WTK, WTV, WTM);
  erF_kernel<<<32, 256, 0, stream>>>(Er, ErF);

  gemm_qkv_kernel<<<dim3(8, 32, 3), 256, 0, stream>>>(QB, KB, VB,
                                                      WTQ, WTK, WTV,
                                                      QW, KF, VF);

  attn_kernel<<<dim3(64, 64), 512, 0, stream>>>(QW, KF, VF, ErF, O);

  gemm_mg_kernel<<<dim3(8, 32), 512, 0, stream>>>(O, WTM, out);
}

// Round 8
// 277.150 us; speedup vs baseline: 2.2117x; 1.0751x over previous
//
#include <hip/hip_runtime.h>

#define H_  16
#define L_  1024
#define D_  1024
#define DH  64

typedef short bf16x8 __attribute__((ext_vector_type(8)));
typedef float f32x4  __attribute__((ext_vector_type(4)));

__device__ __forceinline__ ushort f2bf(float f) {
  union { float f; unsigned int u; } x; x.f = f;
  unsigned int u = x.u;
  u = (u + 0x7fffu + ((u >> 16) & 1u)) >> 16;   // RNE
  return (ushort)u;
}
__device__ __forceinline__ float bf2f(ushort s) {
  union { unsigned int u; float f; } x; x.u = ((unsigned int)s) << 16;
  return x.f;
}

// Fragment-interleaved (AF) layout for an M x 1024 bf16 matrix:
// chunk (mb=m>>7, kb=k>>5, am=(m>>4)&7) of 512 ushort; within: lane=((k>>3)&3)*16+(m&15), jj=k&7.
// One 64-lane x 16B load at chunk base + lane*16 IS an MFMA A/B fragment.
__device__ __forceinline__ size_t afi(int m, int k) {
  return (((size_t)((m >> 7) * 32 + (k >> 5)) * 8 + ((m >> 4) & 7)) << 9)
       + ((size_t)((((k >> 3) & 3) << 4) + (m & 15)) << 3) + (k & 7);
}

// async global->LDS 16B per lane: dst = (wave-uniform) l + lane*16, src = per-lane g.
__device__ __forceinline__ void gl_lds16(const ushort* g, ushort* l) {
  __builtin_amdgcn_global_load_lds(
      (const __attribute__((address_space(1))) void*)g,
      (__attribute__((address_space(3))) void*)l, 16, 0, 0);
}

// q/k/v fp32 row-major -> bf16 AF layout.
__global__ __launch_bounds__(256) void cvt3_kernel(
    const float* __restrict__ q, const float* __restrict__ k, const float* __restrict__ v,
    ushort* __restrict__ qb, ushort* __restrict__ kb, ushort* __restrict__ vb) {
  const int z = blockIdx.y;
  const float* in = (z == 0) ? q : (z == 1) ? k : v;
  ushort* out = (z == 0) ? qb : (z == 1) ? kb : vb;
  int idx = (blockIdx.x * 256 + threadIdx.x) * 8;
  int m = idx >> 10, kk = idx & 1023;
  float4 f0 = *(const float4*)(in + idx);
  float4 f1 = *(const float4*)(in + idx + 4);
  ushort u[8] = {f2bf(f0.x), f2bf(f0.y), f2bf(f0.z), f2bf(f0.w),
                 f2bf(f1.x), f2bf(f1.y), f2bf(f1.z), f2bf(f1.w)};
  *(uint4*)(out + afi(m, kk)) = *(uint4*)u;
}

// Er fp32 [1024][64] -> ErF fragment-interleaved bf16 (attn-style fragments).
__global__ __launch_bounds__(256) void erF_kernel(const float* __restrict__ Er,
                                                  ushort* __restrict__ ErF) {
  int t = blockIdx.x * 256 + threadIdx.x;   // [0, 8192)
  int lane = t & 63, ph = (t >> 6) & 1, jg = t >> 7;
  int m = jg * 16 + (lane & 15);
  int k = ph * 32 + (lane >> 4) * 8;
  float4 f0 = *(const float4*)(Er + m * 64 + k);
  float4 f1 = *(const float4*)(Er + m * 64 + k + 4);
  ushort4 u0, u1;
  u0.x = f2bf(f0.x); u0.y = f2bf(f0.y); u0.z = f2bf(f0.z); u0.w = f2bf(f0.w);
  u1.x = f2bf(f1.x); u1.y = f2bf(f1.y); u1.z = f2bf(f1.z); u1.w = f2bf(f1.w);
  *(ushort4*)(ErF + t * 8)     = u0;
  *(ushort4*)(ErF + t * 8 + 4) = u1;
}

// 4 weight transposes fused: W fp32 [k][n] -> WT bf16 AF layout of BT[n][k].
__global__ __launch_bounds__(256) void wT4_kernel(
    const float* __restrict__ W0, const float* __restrict__ W1,
    const float* __restrict__ W2, const float* __restrict__ W3,
    ushort* __restrict__ T0, ushort* __restrict__ T1,
    ushort* __restrict__ T2, ushort* __restrict__ T3) {
  __shared__ ushort tt[64][72];
  const int z = blockIdx.z;
  const float* W = (z == 0) ? W0 : (z == 1) ? W1 : (z == 2) ? W2 : W3;
  ushort*     WT = (z == 0) ? T0 : (z == 1) ? T1 : (z == 2) ? T2 : T3;
  const int t = threadIdx.x;
  const int k0 = blockIdx.y * 64, n0 = blockIdx.x * 64;
#pragma unroll
  for (int c = 0; c < 4; ++c) {
    int k = c * 16 + (t >> 4);
    float4 f = *(const float4*)(W + (size_t)(k0 + k) * 1024 + n0 + (t & 15) * 4);
    tt[(t & 15) * 4 + 0][k] = f2bf(f.x);
    tt[(t & 15) * 4 + 1][k] = f2bf(f.y);
    tt[(t & 15) * 4 + 2][k] = f2bf(f.z);
    tt[(t & 15) * 4 + 3][k] = f2bf(f.w);
  }
  __syncthreads();
#pragma unroll
  for (int p = 0; p < 2; ++p) {
    int n = p * 32 + (t >> 3);
    *(uint4*)(WT + afi(n0 + n, k0 + (t & 7) * 8)) = *(const uint4*)(&tt[n][(t & 7) * 8]);
  }
}

// Fused Q/K/V projection GEMM, m97-style: AF operands, global_load_lds staging.
// z=0: QW bf16 row-major; z=1: KF attn-fragments; z=2: VF attn-fragments.
__global__ __launch_bounds__(256) void gemm_qkv_kernel(
    const ushort* __restrict__ Aq, const ushort* __restrict__ Ak, const ushort* __restrict__ Av,
    const ushort* __restrict__ BTq, const ushort* __restrict__ BTk, const ushort* __restrict__ BTv,
    ushort* __restrict__ Cq, ushort* __restrict__ Ck, ushort* __restrict__ Cv) {
  __shared__ ushort lsA[4096];
  __shared__ ushort lsB[4096];
  const int z = blockIdx.z;
  const ushort* A  = (z == 0) ? Aq  : (z == 1) ? Ak  : Av;
  const ushort* BT = (z == 0) ? BTq : (z == 1) ? BTk : BTv;
  ushort*       Cp = (z == 0) ? Cq  : (z == 1) ? Ck  : Cv;

  const int tid  = threadIdx.x;
  const int w    = tid >> 6, lane = tid & 63, qd = lane >> 4, ln = lane & 15;
  const int rw   = w >> 1, cw = w & 1;
  const int mb   = blockIdx.y, nb = blockIdx.x;
  const int m0   = mb * 128, n0 = nb * 128;

  f32x4 acc[16];
#pragma unroll
  for (int i = 0; i < 16; ++i) acc[i] = (f32x4){0.f, 0.f, 0.f, 0.f};

  for (int kb = 0; kb < 32; ++kb) {
    const ushort* Ab = A  + ((size_t)(mb * 32 + kb) << 12);
    const ushort* Bb = BT + ((size_t)(nb * 32 + kb) << 12);
    const int c0 = 2 * w;
    gl_lds16(Ab + ((size_t)c0 << 9) + lane * 8,        lsA + (c0 << 9));
    gl_lds16(Ab + ((size_t)(c0 + 1) << 9) + lane * 8,  lsA + ((c0 + 1) << 9));
    gl_lds16(Bb + ((size_t)c0 << 9) + lane * 8,        lsB + (c0 << 9));
    gl_lds16(Bb + ((size_t)(c0 + 1) << 9) + lane * 8,  lsB + ((c0 + 1) << 9));
    __syncthreads();
    bf16x8 afr[4], bfr[4];
#pragma unroll
    for (int am = 0; am < 4; ++am)
      afr[am] = *(const bf16x8*)(lsA + ((rw * 4 + am) << 9) + lane * 8);
#pragma unroll
    for (int bn = 0; bn < 4; ++bn)
      bfr[bn] = *(const bf16x8*)(lsB + ((cw * 4 + bn) << 9) + lane * 8);
#pragma unroll
    for (int am = 0; am < 4; ++am)
#pragma unroll
      for (int bn = 0; bn < 4; ++bn)
        acc[am * 4 + bn] = __builtin_amdgcn_mfma_f32_16x16x32_bf16(afr[am], bfr[bn], acc[am * 4 + bn], 0, 0, 0);
    __syncthreads();
  }
#pragma unroll
  for (int am = 0; am < 4; ++am)
#pragma unroll
    for (int bn = 0; bn < 4; ++bn) {
      const int rbase = m0 + rw * 64 + am * 16 + qd * 4;
      const int colg  = n0 + cw * 64 + bn * 16 + ln;
      if (z == 0) {
#pragma unroll
        for (int r = 0; r < 4; ++r)
          Cp[(size_t)(rbase + r) * 1024 + colg] = f2bf(acc[am * 4 + bn][r]);
      } else if (z == 1) {
        const int bh  = rbase >> 6;
        const int ki0 = rbase & 63;
        const int jg  = colg >> 4;
        const int ph  = ki0 >> 5;
        const int lanep = ((ki0 >> 3) & 3) * 16 + (colg & 15);
        const int jj0 = ki0 & 7;
        ushort4 u;
        u.x = f2bf(acc[am * 4 + bn][0]); u.y = f2bf(acc[am * 4 + bn][1]);
        u.z = f2bf(acc[am * 4 + bn][2]); u.w = f2bf(acc[am * 4 + bn][3]);
        *(ushort4*)(Cp + (size_t)bh * 65536 + (size_t)((jg * 2 + ph) * 64 + lanep) * 8 + jj0) = u;
      } else {
        const int bh = rbase >> 6;
        const int llow = colg >> 6, dd = colg & 63;
        const int g = dd >> 4, lnf = dd & 15;
#pragma unroll
        for (int r = 0; r < 4; ++r) {
          int l = ((rbase + r) & 63) * 16 + llow;
          int ks = l >> 5;
          int lanep = ((l >> 3) & 3) * 16 + lnf;
          int jj = l & 7;
          Cp[(size_t)bh * 65536 + (size_t)((g * 32 + ks) * 64 + lanep) * 8 + jj] = f2bf(acc[am * 4 + bn][r]);
        }
      }
    }
}

// Merge GEMM, in-block split-K (8 waves; stream ts=w>>2), m97-style staging. A and BT in AF layout.
__global__ __launch_bounds__(512) void gemm_mg_kernel(const ushort* __restrict__ A,
                                                      const ushort* __restrict__ BT,
                                                      float* __restrict__ Cp) {
  __shared__ ushort lsA[2][4096];
  __shared__ ushort lsB[2][4096];
  __shared__ float  mgred[256 * 33];
  const int tid  = threadIdx.x;
  const int w    = tid >> 6, lane = tid & 63, qd = lane >> 4, ln = lane & 15;
  const int kh   = w >> 2, q = w & 3;
  const int rw   = q >> 1, cw = q & 1;
  const int mb   = blockIdx.y, nb = blockIdx.x;
  const int m0   = mb * 128, n0 = nb * 128;

  f32x4 acc[16];
#pragma unroll
  for (int i = 0; i < 16; ++i) acc[i] = (f32x4){0.f, 0.f, 0.f, 0.f};

  for (int kb = 0; kb < 16; ++kb) {
    const int kbi = kh * 16 + kb;
    const ushort* Ab = A  + ((size_t)(mb * 32 + kbi) << 12);
    const ushort* Bb = BT + ((size_t)(nb * 32 + kbi) << 12);
    const int c0 = 2 * q;
    gl_lds16(Ab + ((size_t)c0 << 9) + lane * 8,        lsA[kh] + (c0 << 9));
    gl_lds16(Ab + ((size_t)(c0 + 1) << 9) + lane * 8,  lsA[kh] + ((c0 + 1) << 9));
    gl_lds16(Bb + ((size_t)c0 << 9) + lane * 8,        lsB[kh] + (c0 << 9));
    gl_lds16(Bb + ((size_t)(c0 + 1) << 9) + lane * 8,  lsB[kh] + ((c0 + 1) << 9));
    __syncthreads();
    bf16x8 afr[4], bfr[4];
#pragma unroll
    for (int am = 0; am < 4; ++am)
      afr[am] = *(const bf16x8*)(lsA[kh] + ((rw * 4 + am) << 9) + lane * 8);
#pragma unroll
    for (int bn = 0; bn < 4; ++bn)
      bfr[bn] = *(const bf16x8*)(lsB[kh] + ((cw * 4 + bn) << 9) + lane * 8);
#pragma unroll
    for (int am = 0; am < 4; ++am)
#pragma unroll
      for (int bn = 0; bn < 4; ++bn)
        acc[am * 4 + bn] = __builtin_amdgcn_mfma_f32_16x16x32_bf16(afr[am], bfr[bn], acc[am * 4 + bn], 0, 0, 0);
    __syncthreads();
  }

  for (int half = 0; half < 2; ++half) {
    __syncthreads();
    if (w >= 4) {
      const int base = ((w - 4) * 64 + lane) * 33;
#pragma unroll
      for (int i = 0; i < 8; ++i)
#pragma unroll
        for (int c = 0; c < 4; ++c) mgred[base + i * 4 + c] = acc[half * 8 + i][c];
    }
    __syncthreads();
    if (w < 4) {
      const int base = (w * 64 + lane) * 33;
#pragma unroll
      for (int i = 0; i < 8; ++i)
#pragma unroll
        for (int c = 0; c < 4; ++c) acc[half * 8 + i][c] += mgred[base + i * 4 + c];
    }
  }
  if (w < 4) {
#pragma unroll
    for (int am = 0; am < 4; ++am)
#pragma unroll
      for (int bn = 0; bn < 4; ++bn) {
        const int rbase = m0 + rw * 64 + am * 16 + qd * 4;
        const int colg  = n0 + cw * 64 + bn * 16 + ln;
#pragma unroll
        for (int r = 0; r < 4; ++r)
          Cp[(size_t)(rbase + r) * 1024 + colg] = acc[am * 4 + bn][r];
      }
  }
}

// Fused relative attention (round-7 structure); O is now written in AF layout for the merge GEMM.
__global__ __launch_bounds__(512, 4) void attn_kernel(
    const ushort* __restrict__ QW, const ushort* __restrict__ KF,
    const ushort* __restrict__ VF, const ushort* __restrict__ ErF,
    ushort* __restrict__ Om) {
  __shared__ ushort qflat[17440];    // QEr rows 0..16 @ r*1025; P rows @ r*1048
  __shared__ float  red[4][64][4];
  __shared__ float  stats[2][8][16];

  const int tid  = threadIdx.x;
  const int w    = tid >> 6;
  const int lane = tid & 63;
  const int qd   = lane >> 4;
  const int ln   = lane & 15;
  const int bh   = blockIdx.y;
  const int i0   = blockIdx.x << 4;
  const ushort* q  = QW + ((size_t)bh << 16);
  const ushort* kf = KF + ((size_t)bh << 16);
  const ushort* vf = VF + ((size_t)bh << 16);

  if (tid < 16) qflat[tid * 1025 + 1024] = 0;   // the j==i+1 zeros

  bf16x8 a00 = *(const bf16x8*)(q + (size_t)(i0 + ln) * 64 + qd * 8);
  bf16x8 a01 = *(const bf16x8*)(q + (size_t)(i0 + ln) * 64 + 32 + qd * 8);
  const int row16 = (i0 + 16 > 1023) ? 1023 : i0 + 16;
  bf16x8 a10 = *(const bf16x8*)(q + (size_t)row16 * 64 + qd * 8);
  bf16x8 a11 = *(const bf16x8*)(q + (size_t)row16 * 64 + 32 + qd * 8);

  const int jg0 = w * 8;

  // ---- phase 0: QEr
#pragma unroll
  for (int f = 0; f < 8; ++f) {
    const int jg = jg0 + f;
    bf16x8 b0 = *(const bf16x8*)(ErF + (size_t)((jg * 2 + 0) * 64 + lane) * 8);
    bf16x8 b1 = *(const bf16x8*)(ErF + (size_t)((jg * 2 + 1) * 64 + lane) * 8);
    f32x4 acc = {0.f, 0.f, 0.f, 0.f};
    acc = __builtin_amdgcn_mfma_f32_16x16x32_bf16(a00, b0, acc, 0, 0, 0);
    acc = __builtin_amdgcn_mfma_f32_16x16x32_bf16(a01, b1, acc, 0, 0, 0);
    const int m = jg * 16 + ln;
#pragma unroll
    for (int r = 0; r < 4; ++r) qflat[(qd * 4 + r) * 1025 + m] = f2bf(acc[r]);
    if (jg * 16 <= 1006 - i0) {
      f32x4 ac2 = {0.f, 0.f, 0.f, 0.f};
      ac2 = __builtin_amdgcn_mfma_f32_16x16x32_bf16(a10, b0, ac2, 0, 0, 0);
      ac2 = __builtin_amdgcn_mfma_f32_16x16x32_bf16(a11, b1, ac2, 0, 0, 0);
      if (qd == 0) qflat[16 * 1025 + m] = f2bf(ac2[0]);
    }
  }

  // ---- phase 1: S = q @ kT
  f32x4 sfr[8];
#pragma unroll
  for (int f = 0; f < 8; ++f) {
    const int jg = jg0 + f;
    bf16x8 b0 = *(const bf16x8*)(kf + (size_t)((jg * 2 + 0) * 64 + lane) * 8);
    bf16x8 b1 = *(const bf16x8*)(kf + (size_t)((jg * 2 + 1) * 64 + lane) * 8);
    f32x4 acc = {0.f, 0.f, 0.f, 0.f};
    acc = __builtin_amdgcn_mfma_f32_16x16x32_bf16(a00, b0, acc, 0, 0, 0);
    acc = __builtin_amdgcn_mfma_f32_16x16x32_bf16(a01, b1, acc, 0, 0, 0);
    sfr[f] = acc;
  }
  __syncthreads();

  // ---- skew-add (branch-free flat gather)
#pragma unroll
  for (int f = 0; f < 8; ++f) {
    const int cj = 1023 - i0 + w * 128 + f * 16 + ln;
#pragma unroll
    for (int r = 0; r < 4; ++r)
      sfr[f][r] += bf2f(qflat[(qd * 4 + r) * 1024 + cj]);
  }

  // ---- row max
  {
    float vm[4];
#pragma unroll
    for (int r = 0; r < 4; ++r) {
      float m = sfr[0][r];
#pragma unroll
      for (int f = 1; f < 8; ++f) m = fmaxf(m, sfr[f][r]);
#pragma unroll
      for (int off = 1; off < 16; off <<= 1) m = fmaxf(m, __shfl_xor(m, off, 64));
      vm[r] = m;
    }
    if (ln == 0) {
#pragma unroll
      for (int r = 0; r < 4; ++r) stats[0][w][qd * 4 + r] = vm[r];
    }
  }
  __syncthreads();
  const float cexp = 0.18033688011112042f;   // 0.125 * log2(e)
  float gm2[4];
#pragma unroll
  for (int r = 0; r < 4; ++r) {
    float m = stats[0][0][qd * 4 + r];
#pragma unroll
    for (int ww = 1; ww < 8; ++ww) m = fmaxf(m, stats[0][ww][qd * 4 + r]);
    gm2[r] = -m * cexp;
  }

  // ---- exp2, sums, P at stride 1048
  float vs[4] = {0.f, 0.f, 0.f, 0.f};
#pragma unroll
  for (int f = 0; f < 8; ++f) {
    const int j = w * 128 + f * 16 + ln;
#pragma unroll
    for (int r = 0; r < 4; ++r) {
      float e = exp2f(fmaf(sfr[f][r], cexp, gm2[r]));
      vs[r] += e;
      qflat[(qd * 4 + r) * 1048 + j] = f2bf(e);
    }
  }
#pragma unroll
  for (int r = 0; r < 4; ++r) {
    float s = vs[r];
#pragma unroll
    for (int off = 1; off < 16; off <<= 1) s += __shfl_xor(s, off, 64);
    if (ln == 0) stats[1][w][qd * 4 + r] = s;
  }
  __syncthreads();
  float rrl[4];
#pragma unroll
  for (int r = 0; r < 4; ++r) {
    float s = 0.f;
#pragma unroll
    for (int ww = 0; ww < 8; ++ww) s += stats[1][ww][qd * 4 + r];
    rrl[r] = 1.0f / s;
  }

  // ---- phase 3: O = P @ v (split-K across wave pairs)
  const int g = w & 3, kh = w >> 2;
  f32x4 oacc = {0.f, 0.f, 0.f, 0.f};
#pragma unroll
  for (int kc = 0; kc < 16; ++kc) {
    const int ks = kh * 16 + kc;
    bf16x8 ap = *(const bf16x8*)(qflat + ln * 1048 + ks * 32 + qd * 8);
    bf16x8 bv = *(const bf16x8*)(vf + (size_t)((g * 32 + ks) * 64 + lane) * 8);
    oacc = __builtin_amdgcn_mfma_f32_16x16x32_bf16(ap, bv, oacc, 0, 0, 0);
  }

  if (w >= 4) {
#pragma unroll
    for (int cc = 0; cc < 4; ++cc) red[w - 4][lane][cc] = oacc[cc];
  }
  __syncthreads();
  if (w < 4) {
    const int b = bh >> 4, h = bh & 15;
    // O in AF layout: m = b*1024 + i0 + qd*4 + r, kg = h*64 + g*16 + ln
    const int kg = h * 64 + g * 16 + ln;
    const int mbase = b * 1024 + i0;
    ushort* ob = Om + (((size_t)((mbase >> 7) * 32 + (kg >> 5)) * 8 + ((mbase >> 4) & 7)) << 9)
               + ((((kg >> 3) & 3) * 16 + qd * 4) << 3) + (kg & 7);
#pragma unroll
    for (int r = 0; r < 4; ++r) {
      float o = oacc[r] + red[w][lane][r];
      ob[r * 8] = f2bf(o * rrl[r]);
    }
  }
}

extern "C" void kernel_launch(void* const* d_in, const int* in_sizes, int n_in,
                              void* d_out, int out_size, void* d_ws, size_t ws_size,
                              hipStream_t stream) {
  const float* query = (const float*)d_in[0];
  const float* key   = (const float*)d_in[1];
  const float* value = (const float*)d_in[2];
  const float* WQ    = (const float*)d_in[3];
  const float* WK    = (const float*)d_in[4];
  const float* WV    = (const float*)d_in[5];
  const float* Er    = (const float*)d_in[6];
  const float* WM    = (const float*)d_in[7];
  float* out = (float*)d_out;

  // workspace (ushort units): QW,KF,VF,O 4M each; ErF 64K; 4 WT 1M each; KB,VB 4M each.
  // QB (bf16 AF query) aliases O: consumed by qkv GEMM before attn writes O (AF).
  ushort* QW  = (ushort*)d_ws;
  ushort* KF  = QW  + (size_t)4096 * 1024;
  ushort* VF  = KF  + (size_t)4096 * 1024;
  ushort* O   = VF  + (size_t)4096 * 1024;
  ushort* ErF = O   + (size_t)4096 * 1024;
  ushort* WTQ = ErF + (size_t)65536;
  ushort* WTK = WTQ + (size_t)1024 * 1024;
  ushort* WTV = WTK + (size_t)1024 * 1024;
  ushort* WTM = WTV + (size_t)1024 * 1024;
  ushort* KB  = WTM + (size_t)1024 * 1024;
  ushort* VB  = KB  + (size_t)4096 * 1024;
  ushort* QB  = O;   // alias

  cvt3_kernel<<<dim3(2048, 3), 256, 0, stream>>>(query, key, value, QB, KB, VB);
  wT4_kernel<<<dim3(16, 16, 4), 256, 0, stream>>>(WQ, WK, WV, WM, WTQ, WTK, WTV, WTM);
  erF_kernel<<<32, 256, 0, stream>>>(Er, ErF);

  gemm_qkv_kernel<<<dim3(8, 32, 3), 256, 0, stream>>>(QB, KB, VB,
                                                      WTQ, WTK, WTV,
                                                      QW, KF, VF);

  attn_kernel<<<dim3(64, 64), 512, 0, stream>>>(QW, KF, VF, ErF, O);

  gemm_mg_kernel<<<dim3(8, 32), 512, 0, stream>>>(O, WTM, out);
}